// Round 8
// baseline (1273.310 us; speedup 1.0000x reference)
//
#include <hip/hip_runtime.h>
#include <hip/hip_bf16.h>

typedef __hip_bfloat16 bf16;
typedef unsigned short u16;
typedef __attribute__((ext_vector_type(8))) short short8;
typedef __attribute__((ext_vector_type(4))) float f32x4;

__device__ inline float b2f(u16 u){ unsigned int x = ((unsigned int)u) << 16; float f; __builtin_memcpy(&f, &x, 4); return f; }
__device__ inline u16 f2bits(float f){ __hip_bfloat16 h = __float2bfloat16(f); u16 u; __builtin_memcpy(&u, &h, 2); return u; }
__device__ inline void unpk(unsigned int w, float& a, float& b){ a = b2f((u16)(w & 0xffffu)); b = b2f((u16)(w >> 16)); }

// pack two fp32 -> bf16x2 (round via +0x8000, then byte-perm) [verified r7]
__device__ __forceinline__ unsigned int pkbf(float a, float b)
{
  unsigned int ua = __float_as_uint(a) + 0x8000u;
  unsigned int ub = __float_as_uint(b) + 0x8000u;
  return __builtin_amdgcn_perm(ub, ua, 0x07060302u);
}

// ---------------------------------------------------------------------------
// dtype detection (verified round 2)
// ---------------------------------------------------------------------------
__global__ __launch_bounds__(512) void detect_k(const unsigned int* __restrict__ raw, int* __restrict__ flag)
{
  __shared__ int cnt;
  if (threadIdx.x == 0) cnt = 0;
  __syncthreads();
  unsigned int w = raw[threadIdx.x];
  unsigned int b = w & 0x7fffu;
  int pat = (b >= 0x2000u && b <= 0x4400u) ? 1 : 0;
#pragma unroll
  for (int o = 32; o; o >>= 1) pat += __shfl_xor(pat, o);
  if ((threadIdx.x & 63) == 0) atomicAdd(&cnt, pat);
  __syncthreads();
  if (threadIdx.x == 0) flag[0] = (cnt > 320) ? 1 : 0;
}

struct CvtArgs { const void* p[55]; int off[56]; int sz[55]; };

// vectorized x8 conversion (verified round 5)
__global__ __launch_bounds__(256) void cvtall8_k(CvtArgs a, bf16* __restrict__ dst,
                                                 const int* __restrict__ flag)
{
  int g8 = blockIdx.x * 256 + threadIdx.x;
  int gid = g8 * 8;
  if (gid >= a.off[55]) return;
  int lo = 0, hi = 54;
  while (lo < hi) { int mid = (lo + hi + 1) >> 1; if (gid >= a.off[mid]) lo = mid; else hi = mid - 1; }
  int t = lo, i = gid - a.off[t];
  int n = a.sz[t];
  uint4 ov;
  if (flag[0]) {
    const u16* src = (const u16*)a.p[t];
    if (i + 8 <= n) {
      ov = *(const uint4*)(src + i);
    } else {
      u16 tmp[8];
#pragma unroll
      for (int j = 0; j < 8; j++) tmp[j] = (i + j < n) ? src[i + j] : (u16)0;
      __builtin_memcpy(&ov, tmp, 16);
    }
  } else {
    const float* src = (const float*)a.p[t];
    float v[8];
    if (i + 8 <= n) {
      uint4 f0 = *(const uint4*)(src + i);
      uint4 f1 = *(const uint4*)(src + i + 4);
      __builtin_memcpy(&v[0], &f0, 16);
      __builtin_memcpy(&v[4], &f1, 16);
    } else {
#pragma unroll
      for (int j = 0; j < 8; j++) v[j] = (i + j < n) ? src[i + j] : 0.f;
    }
    u16 o8[8];
#pragma unroll
    for (int j = 0; j < 8; j++) o8[j] = f2bits(v[j]);
    __builtin_memcpy(&ov, o8, 16);
  }
  *(uint4*)((u16*)dst + gid) = ov;
}

// ---------------------------------------------------------------------------
// 64-tile GEMM (verified r2) + register prefetch (verified r6)
// mode: 0 plain(+bias), 1 +bias+extra, 2 gelu(+bias), 3 scale, 4 +bias+res, 5 sigmoid
// ---------------------------------------------------------------------------
__global__ __launch_bounds__(256) void gemm_k(
    const bf16* __restrict__ A, int lda, long long sAb, long long sAh,
    const bf16* __restrict__ B, int ldb, long long sBb, long long sBh,
    bf16* __restrict__ C, int ldc, long long sCb, long long sCh,
    int M, int N, int K, int HZ,
    const bf16* __restrict__ bias,
    const bf16* __restrict__ res, int ldres,
    const float* __restrict__ extra, int extraDiv,
    float alpha, int mode)
{
  __shared__ u16 As[64][40];
  __shared__ u16 Bs[64][40];
  int z = blockIdx.z;
  int bz = z / HZ, hz = z - bz * HZ;
  A += (size_t)bz * sAb + (size_t)hz * sAh;
  B += (size_t)bz * sBb + (size_t)hz * sBh;
  C += (size_t)bz * sCb + (size_t)hz * sCh;

  int m0 = blockIdx.y * 64, n0 = blockIdx.x * 64;
  int t = threadIdx.x;
  int r = t >> 2, c0 = (t & 3) << 3;
  int lane = t & 63, wv = t >> 6, lr = lane & 15, lq = lane >> 4;

  f32x4 acc[4];
#pragma unroll
  for (int i = 0; i < 4; i++) acc[i] = (f32x4){0.f, 0.f, 0.f, 0.f};

  const u16* Ag = (const u16*)A;
  const u16* Bg = (const u16*)B;
  bool aok = (m0 + r < M), bok = (n0 + r < N);
  const u16* arow = Ag + (size_t)(m0 + r) * lda + c0;
  const u16* brow = Bg + (size_t)(n0 + r) * ldb + c0;

  uint4 av = {0u,0u,0u,0u}, bv = {0u,0u,0u,0u};
  if (aok) av = *(const uint4*)(arow);
  if (bok) bv = *(const uint4*)(brow);

  for (int kt = 0; kt < K; kt += 32) {
    __syncthreads();
    *(uint4*)&As[r][c0] = av;
    *(uint4*)&Bs[r][c0] = bv;
    uint4 av2 = {0u,0u,0u,0u}, bv2 = {0u,0u,0u,0u};
    int nk = kt + 32;
    if (nk < K) {
      if (aok) av2 = *(const uint4*)(arow + nk);
      if (bok) bv2 = *(const uint4*)(brow + nk);
    }
    __syncthreads();
    short8 af = *(const short8*)&As[wv * 16 + lr][lq * 8];
#pragma unroll
    for (int nt = 0; nt < 4; nt++) {
      short8 bfr = *(const short8*)&Bs[nt * 16 + lr][lq * 8];
      acc[nt] = __builtin_amdgcn_mfma_f32_16x16x32_bf16(af, bfr, acc[nt], 0, 0, 0);
    }
    av = av2; bv = bv2;
  }

#pragma unroll
  for (int nt = 0; nt < 4; nt++) {
    int nn = n0 + nt * 16 + lr;
    if (nn >= N) continue;
    float bb = bias ? (float)bias[nn] : 0.f;
#pragma unroll
    for (int rr = 0; rr < 4; rr++) {
      int mm = m0 + wv * 16 + lq * 4 + rr;
      if (mm >= M) continue;
      float v = acc[nt][rr] * alpha + bb;
      if (mode == 1)      v += extra[(mm / extraDiv) * 512 + nn];
      else if (mode == 2) v = 0.5f * v * (1.f + erff(v * 0.70710678118654752f));
      else if (mode == 4) v += (float)res[(size_t)mm * ldres + nn];
      else if (mode == 5) v = 1.f / (1.f + expf(-v));
      C[(size_t)mm * ldc + nn] = __float2bfloat16(v);
    }
  }
}

// ---------------------------------------------------------------------------
// 128x128 GEMM, VGPR-roundtrip staging + register prefetch (r6 pattern),
// padded [.][40] LDS (r2-proven layout). Requires M%128==0,N%128==0,K%32==0.
// ---------------------------------------------------------------------------
__global__ __launch_bounds__(256) void gemm128p_k(
    const bf16* __restrict__ A, int lda,
    const bf16* __restrict__ B, int ldb,
    bf16* __restrict__ C, int ldc, int K,
    const bf16* __restrict__ bias,
    const bf16* __restrict__ res, int ldres,
    const float* __restrict__ extra, int extraDiv,
    float alpha, int mode)
{
  __shared__ u16 As[128][40];
  __shared__ u16 Bs[128][40];
  int t = threadIdx.x, lane = t & 63, w = t >> 6;
  int m0 = blockIdx.y * 128, n0 = blockIdx.x * 128;
  int wm = (w & 1) * 64, wn = (w >> 1) * 64;
  int lr = lane & 15, lq = lane >> 4;
  int r = t >> 2, c0 = (t & 3) << 3;

  const u16* Ag = (const u16*)A;
  const u16* Bg = (const u16*)B;
  const u16* ar0 = Ag + (size_t)(m0 + r) * lda + c0;
  const u16* ar1 = Ag + (size_t)(m0 + 64 + r) * lda + c0;
  const u16* br0 = Bg + (size_t)(n0 + r) * ldb + c0;
  const u16* br1 = Bg + (size_t)(n0 + 64 + r) * ldb + c0;

  uint4 a0 = *(const uint4*)ar0, a1 = *(const uint4*)ar1;
  uint4 b0 = *(const uint4*)br0, b1 = *(const uint4*)br1;

  f32x4 acc[4][4];
#pragma unroll
  for (int i = 0; i < 4; i++)
#pragma unroll
    for (int j = 0; j < 4; j++) acc[i][j] = (f32x4){0.f, 0.f, 0.f, 0.f};

  for (int kt = 0; kt < K; kt += 32) {
    __syncthreads();
    *(uint4*)&As[r][c0] = a0;
    *(uint4*)&As[64 + r][c0] = a1;
    *(uint4*)&Bs[r][c0] = b0;
    *(uint4*)&Bs[64 + r][c0] = b1;
    int nk = kt + 32;
    if (nk < K) {
      a0 = *(const uint4*)(ar0 + nk); a1 = *(const uint4*)(ar1 + nk);
      b0 = *(const uint4*)(br0 + nk); b1 = *(const uint4*)(br1 + nk);
    }
    __syncthreads();
    short8 af[4], bfv[4];
#pragma unroll
    for (int i = 0; i < 4; i++) {
      af[i] = *(const short8*)&As[wm + i * 16 + lr][lq * 8];
      bfv[i] = *(const short8*)&Bs[wn + i * 16 + lr][lq * 8];
    }
#pragma unroll
    for (int mt = 0; mt < 4; mt++)
#pragma unroll
      for (int nt = 0; nt < 4; nt++)
        acc[mt][nt] = __builtin_amdgcn_mfma_f32_16x16x32_bf16(af[mt], bfv[nt], acc[mt][nt], 0, 0, 0);
  }

#pragma unroll
  for (int nt = 0; nt < 4; nt++) {
    int nn = n0 + wn + nt * 16 + lr;
    float bb = bias ? (float)bias[nn] : 0.f;
#pragma unroll
    for (int mt = 0; mt < 4; mt++) {
#pragma unroll
      for (int r2 = 0; r2 < 4; r2++) {
        int mm = m0 + wm + mt * 16 + lq * 4 + r2;
        float v = acc[mt][nt][r2] * alpha + bb;
        if (mode == 1)      v += extra[(mm / extraDiv) * 512 + nn];
        else if (mode == 2) v = 0.5f * v * (1.f + erff(v * 0.70710678118654752f));
        else if (mode == 4) v += (float)res[(size_t)mm * ldres + nn];
        else if (mode == 5) v = 1.f / (1.f + expf(-v));
        C[(size_t)mm * ldc + nn] = __float2bfloat16(v);
      }
    }
  }
}

// ---------------------------------------------------------------------------
// Flash v4: fixed-max split-K, XOR-swizzled LDS (r7), mask = packed-u16 AND
// after exp (replaces additive -1e30), l via ones-MFMA (no VALU row sums).
// ---------------------------------------------------------------------------
__device__ __forceinline__ int swz(int row, int cg)
{
  return row * 64 + ((cg ^ (row & 3) ^ (((row >> 3) & 1) << 2)) << 3);
}

__global__ __launch_bounds__(256) void flash_k(
    const bf16* __restrict__ Qp, long long sQb,
    const bf16* __restrict__ Kp, long long sKb,
    const bf16* __restrict__ VTp, long long sVz,
    float* __restrict__ oAcc, long long sOb,
    float* __restrict__ lAcc, int Ml,
    const int* __restrict__ fog,
    int tilesPerSplit, int SkLen)
{
  __shared__ u16 Kl[64 * 64];
  __shared__ u16 Vl[64 * 64];
  __shared__ u16 fgl16[2304];

  const float SC = 0.125f * 1.44269504088896340736f;
  int z = blockIdx.y, b = z >> 3, h = z & 7;
  int qt = blockIdx.x;
  int kt0 = blockIdx.z * tilesPerSplit;
  int t = threadIdx.x, lane = t & 63, w = t >> 6;
  int lr = lane & 15, lq = lane >> 4;
  int useMask = (fog != nullptr);

  const u16* Qg = (const u16*)Qp + (size_t)b * sQb + h * 64;
  const u16* Kg = (const u16*)Kp + (size_t)b * sKb + h * 64;
  const u16* Vg = (const u16*)VTp + (size_t)z * sVz;

  if (useMask) {
    for (int j = t; j < SkLen; j += 256) fgl16[j] = fog[b * 2304 + j] ? 0xFFFFu : 0u;
  }

  int qrow = qt * 64 + w * 16 + lr;
  short8 qf0, qf1;
  {
    union { short8 s; u16 u[8]; } i0, i1, o0, o1;
    i0.s = *(const short8*)(Qg + (size_t)qrow * 512 + lq * 8);
    i1.s = *(const short8*)(Qg + (size_t)qrow * 512 + 32 + lq * 8);
#pragma unroll
    for (int j = 0; j < 8; j++) {
      o0.u[j] = f2bits(b2f(i0.u[j]) * SC);
      o1.u[j] = f2bits(b2f(i1.u[j]) * SC);
    }
    qf0 = o0.s; qf1 = o1.s;
  }

  short8 ones8;
  {
    union { short8 s; u16 u[8]; } on;
#pragma unroll
    for (int j = 0; j < 8; j++) on.u[j] = 0x3F80u;
    ones8 = on.s;
  }

  int rowA[4], kAd0[4], kAd1[4];
#pragma unroll
  for (int nt = 0; nt < 4; nt++) {
    rowA[nt] = 32 * (nt >> 1) + 8 * (lr >> 2) + 4 * (nt & 1) + (lr & 3);
    kAd0[nt] = swz(rowA[nt], lq);
    kAd1[nt] = swz(rowA[nt], lq + 4);
  }
  int vAd0[4], vAd1[4];
#pragma unroll
  for (int dt = 0; dt < 4; dt++) {
    vAd0[dt] = swz(dt * 16 + lr, lq);
    vAd1[dt] = swz(dt * 16 + lr, lq + 4);
  }

  f32x4 o[4], ol;
#pragma unroll
  for (int i = 0; i < 4; i++) o[i] = (f32x4){0.f, 0.f, 0.f, 0.f};
  ol = (f32x4){0.f, 0.f, 0.f, 0.f};

  int rr = t >> 2, cg = t & 3, cs = cg * 8;
  int wAd0 = swz(rr, cg), wAd1 = swz(rr, cg + 4);
  for (int kti = 0; kti < tilesPerSplit; kti++) {
    int kt = kt0 + kti;
    __syncthreads();
    const u16* krow = Kg + (size_t)(kt * 64 + rr) * 512;
    const u16* vrow = Vg + (size_t)rr * SkLen + kt * 64;
    *(uint4*)&Kl[wAd0] = *(const uint4*)(krow + cs);
    *(uint4*)&Kl[wAd1] = *(const uint4*)(krow + cs + 32);
    *(uint4*)&Vl[wAd0] = *(const uint4*)(vrow + cs);
    *(uint4*)&Vl[wAd1] = *(const uint4*)(vrow + cs + 32);
    __syncthreads();

    f32x4 s[4];
#pragma unroll
    for (int nt = 0; nt < 4; nt++) {
      s[nt] = (f32x4){0.f, 0.f, 0.f, 0.f};
      short8 kf0 = *(const short8*)&Kl[kAd0[nt]];
      short8 kf1 = *(const short8*)&Kl[kAd1[nt]];
      s[nt] = __builtin_amdgcn_mfma_f32_16x16x32_bf16(kf0, qf0, s[nt], 0, 0, 0);
      s[nt] = __builtin_amdgcn_mfma_f32_16x16x32_bf16(kf1, qf1, s[nt], 0, 0, 0);
    }

    union { unsigned int u[4]; short8 s8; } pk0, pk1;
#pragma unroll
    for (int nt = 0; nt < 4; nt++) {
      float p0 = exp2f(s[nt][0]), p1 = exp2f(s[nt][1]);
      float p2 = exp2f(s[nt][2]), p3 = exp2f(s[nt][3]);
      unsigned int w0 = pkbf(p0, p1);
      unsigned int w1 = pkbf(p2, p3);
      if (useMask) {
        int key = kt * 64 + 32 * (nt >> 1) + 8 * lq + 4 * (nt & 1);
        uint2 mm = *(const uint2*)&fgl16[key];   // broadcast within quad-group
        w0 &= mm.x; w1 &= mm.y;
      }
      if (nt < 2) { pk0.u[(nt & 1) * 2] = w0; pk0.u[(nt & 1) * 2 + 1] = w1; }
      else        { pk1.u[(nt & 1) * 2] = w0; pk1.u[(nt & 1) * 2 + 1] = w1; }
    }
#pragma unroll
    for (int dt = 0; dt < 4; dt++) {
      short8 vf0 = *(const short8*)&Vl[vAd0[dt]];
      short8 vf1 = *(const short8*)&Vl[vAd1[dt]];
      o[dt] = __builtin_amdgcn_mfma_f32_16x16x32_bf16(pk0.s8, vf0, o[dt], 0, 0, 0);
      o[dt] = __builtin_amdgcn_mfma_f32_16x16x32_bf16(pk1.s8, vf1, o[dt], 0, 0, 0);
    }
    ol = __builtin_amdgcn_mfma_f32_16x16x32_bf16(pk0.s8, ones8, ol, 0, 0, 0);
    ol = __builtin_amdgcn_mfma_f32_16x16x32_bf16(pk1.s8, ones8, ol, 0, 0, 0);
  }

  // l: C-layout row=lq*4+r2, all cols identical -> lanes lr==0 write 4 rows
  if (lr == 0) {
#pragma unroll
    for (int r2 = 0; r2 < 4; r2++)
      atomicAdd(&lAcc[z * Ml + qt * 64 + w * 16 + lq * 4 + r2], ol[r2]);
  }

  float* ob = oAcc + (size_t)b * sOb;
  int qb = qt * 64 + w * 16 + lq * 4;
#pragma unroll
  for (int dt = 0; dt < 4; dt++)
#pragma unroll
    for (int r2 = 0; r2 < 4; r2++)
      atomicAdd(&ob[(size_t)(qb + r2) * 512 + h * 64 + dt * 16 + lr], o[dt][r2]);
}

// normalize, vectorized x4
__global__ __launch_bounds__(256) void fdiv4_k(const float* __restrict__ oAcc,
                                               const float* __restrict__ lAcc,
                                               int Mq, int Ml, int rows,
                                               bf16* __restrict__ out)
{
  int i = (blockIdx.x * 256 + threadIdx.x) * 4;
  if (i >= rows * 512) return;
  int row = i >> 9, col = i & 511;
  int b = row / Mq, q = row - b * Mq;
  int zz = b * 8 + (col >> 6);
  float l = lAcc[zz * Ml + q];
  float inv = (l > 0.f) ? 1.f / l : 0.f;
  float4 v = *(const float4*)(oAcc + i);
  u16 o4[4] = {f2bits(v.x * inv), f2bits(v.y * inv), f2bits(v.z * inv), f2bits(v.w * inv)};
  unsigned int lo = o4[0] | ((unsigned)o4[1] << 16);
  unsigned int hi = o4[2] | ((unsigned)o4[3] << 16);
  *(uint2*)((u16*)out + i) = (uint2){lo, hi};
}

// in [R,C] row-major -> out [C,Rpad], zero-filled for src rows >= R
__global__ __launch_bounds__(256) void transpose_k(const bf16* __restrict__ in, bf16* __restrict__ out,
                                                   int R, int C, int Rpad, long long inB, long long outB)
{
  __shared__ u16 tile[32][33];
  const u16* ip = (const u16*)in + (size_t)blockIdx.z * inB;
  u16* op = (u16*)out + (size_t)blockIdx.z * outB;
  int c0 = blockIdx.x * 32, r0 = blockIdx.y * 32;
  int tx = threadIdx.x & 31, ty = threadIdx.x >> 5;
#pragma unroll
  for (int j = 0; j < 4; j++) {
    int rr = r0 + ty + j * 8, cc = c0 + tx;
    u16 v = 0;
    if (rr < R && cc < C) v = ip[(size_t)rr * C + cc];
    tile[ty + j * 8][tx] = v;
  }
  __syncthreads();
#pragma unroll
  for (int j = 0; j < 4; j++) {
    int oc = c0 + ty + j * 8;
    if (oc < C && r0 + tx < Rpad) op[(size_t)oc * Rpad + r0 + tx] = tile[tx][ty + j * 8];
  }
}

__global__ __launch_bounds__(256) void headT_k(const bf16* __restrict__ in, bf16* __restrict__ out,
                                               int Sk, int rowbase, int bstride)
{
  __shared__ u16 tile[32][33];
  int z = blockIdx.z, b = z >> 3, h = z & 7;
  const u16* ip = (const u16*)in + ((size_t)(rowbase + b * bstride)) * 512 + h * 64;
  u16* op = (u16*)out + (size_t)z * 64 * Sk;
  int r0 = blockIdx.x * 32, c0 = blockIdx.y * 32;
  int tx = threadIdx.x & 31, ty = threadIdx.x >> 5;
#pragma unroll
  for (int j = 0; j < 4; j++)
    tile[ty + j * 8][tx] = ip[(size_t)(r0 + ty + j * 8) * 512 + c0 + tx];
  __syncthreads();
#pragma unroll
  for (int j = 0; j < 4; j++)
    op[(size_t)(c0 + ty + j * 8) * Sk + r0 + tx] = tile[tx][ty + j * 8];
}

// row LayerNorm over D=512, 4 rows/block (wave per row)
__global__ __launch_bounds__(256) void ln_k(const bf16* __restrict__ in, const bf16* __restrict__ g,
                                            const bf16* __restrict__ bb, bf16* __restrict__ out)
{
  size_t row = blockIdx.x * 4 + (threadIdx.x >> 6);
  int lane = threadIdx.x & 63;
  const u16* ip = (const u16*)in + row * 512 + lane * 8;
  uint4 rv = *(const uint4*)ip;
  float v[8];
  unpk(rv.x, v[0], v[1]); unpk(rv.y, v[2], v[3]); unpk(rv.z, v[4], v[5]); unpk(rv.w, v[6], v[7]);
  float s = 0.f, s2 = 0.f;
#pragma unroll
  for (int k = 0; k < 8; k++) { s += v[k]; s2 += v[k] * v[k]; }
#pragma unroll
  for (int o = 32; o; o >>= 1) { s += __shfl_xor(s, o); s2 += __shfl_xor(s2, o); }
  float mean = s * (1.f / 512.f);
  float var = s2 * (1.f / 512.f) - mean * mean;
  float rstd = rsqrtf(var + 1e-5f);
  uint4 gv = *(const uint4*)((const u16*)g + lane * 8);
  uint4 bv = *(const uint4*)((const u16*)bb + lane * 8);
  float gf[8], bf2[8];
  unpk(gv.x, gf[0], gf[1]); unpk(gv.y, gf[2], gf[3]); unpk(gv.z, gf[4], gf[5]); unpk(gv.w, gf[6], gf[7]);
  unpk(bv.x, bf2[0], bf2[1]); unpk(bv.y, bf2[2], bf2[3]); unpk(bv.z, bf2[4], bf2[5]); unpk(bv.w, bf2[6], bf2[7]);
  u16 o8[8];
#pragma unroll
  for (int k = 0; k < 8; k++) o8[k] = f2bits((v[k] - mean) * rstd * gf[k] + bf2[k]);
  uint4 ov;
  ov.x = o8[0] | ((unsigned)o8[1] << 16); ov.y = o8[2] | ((unsigned)o8[3] << 16);
  ov.z = o8[4] | ((unsigned)o8[5] << 16); ov.w = o8[6] | ((unsigned)o8[7] << 16);
  *(uint4*)((u16*)out + row * 512 + lane * 8) = ov;
}

__global__ void glob_k(const bf16* __restrict__ gf, const bf16* __restrict__ gw,
                       const bf16* __restrict__ gb, float* __restrict__ out)
{
  int i = blockIdx.x * 256 + threadIdx.x; if (i >= 1024) return;
  int b = i >> 9, d = i & 511;
  float s = (float)gb[d];
#pragma unroll
  for (int f = 0; f < 7; f++) s += (float)gf[b * 7 + f] * (float)gw[f * 512 + d];
  out[i] = s;
}

__global__ void padA_k(const bf16* __restrict__ in, bf16* __restrict__ out)
{
  int i = blockIdx.x * 256 + threadIdx.x; if (i >= 4608 * 160) return;
  int r = i / 160, c = i - r * 160;
  out[i] = (c < 150) ? in[r * 150 + c] : __float2bfloat16(0.f);
}

__global__ void catg_k(const bf16* __restrict__ mem, const bf16* __restrict__ mu, bf16* __restrict__ out)
{
  int i = blockIdx.x * 256 + threadIdx.x; if (i >= 256 * 1024) return;
  int r = i >> 10, c = i & 1023;
  out[i] = (c < 512) ? mem[r * 512 + c] : mu[r * 512 + c - 512];
}

__global__ void gcomb_k(const bf16* __restrict__ g, const bf16* __restrict__ mu,
                        const bf16* __restrict__ mem, bf16* __restrict__ out)
{
  int i = blockIdx.x * 256 + threadIdx.x; if (i >= 131072) return;
  float gg = (float)g[i];
  out[i] = __float2bfloat16(gg * (float)mu[i] + (1.f - gg) * (float)mem[i]);
}

__global__ __launch_bounds__(64) void plog_k(const bf16* __restrict__ x, const bf16* __restrict__ pw,
                                             const bf16* __restrict__ pb, float* __restrict__ out)
{
  size_t row = blockIdx.x; int lane = threadIdx.x;
  uint4 xv = *(const uint4*)((const u16*)x + row * 512 + lane * 8);
  uint4 wv = *(const uint4*)((const u16*)pw + lane * 8);
  float v[8], w[8];
  unpk(xv.x, v[0], v[1]); unpk(xv.y, v[2], v[3]); unpk(xv.z, v[4], v[5]); unpk(xv.w, v[6], v[7]);
  unpk(wv.x, w[0], w[1]); unpk(wv.y, w[2], w[3]); unpk(wv.z, w[4], w[5]); unpk(wv.w, w[6], w[7]);
  float s = 0.f;
#pragma unroll
  for (int k = 0; k < 8; k++) s += v[k] * w[k];
#pragma unroll
  for (int o = 32; o; o >>= 1) s += __shfl_xor(s, o);
  if (lane == 0) out[row] = s + (float)pb[0];
}

__global__ __launch_bounds__(256) void psm_k(const float* __restrict__ lg, float* __restrict__ pw)
{
  __shared__ float red[4];
  int b = blockIdx.x, tid = threadIdx.x;
  const float* p = lg + b * 2304;
  float vals[9]; float mx = -3e38f;
#pragma unroll
  for (int i = 0; i < 9; i++) {
    int j = tid + i * 256;
    float x = (j < 2304) ? p[j] : -3e38f;
    vals[i] = x; mx = fmaxf(mx, x);
  }
#pragma unroll
  for (int o = 32; o; o >>= 1) mx = fmaxf(mx, __shfl_xor(mx, o));
  if ((tid & 63) == 0) red[tid >> 6] = mx;
  __syncthreads();
  mx = fmaxf(fmaxf(red[0], red[1]), fmaxf(red[2], red[3]));
  float sum = 0.f;
#pragma unroll
  for (int i = 0; i < 9; i++) {
    int j = tid + i * 256;
    if (j < 2304) { float e = expf(vals[i] - mx); vals[i] = e; sum += e; }
  }
  __syncthreads();
#pragma unroll
  for (int o = 32; o; o >>= 1) sum += __shfl_xor(sum, o);
  if ((tid & 63) == 0) red[tid >> 6] = sum;
  __syncthreads();
  sum = red[0] + red[1] + red[2] + red[3];
  float inv = 1.f / sum;
#pragma unroll
  for (int i = 0; i < 9; i++) {
    int j = tid + i * 256;
    if (j < 2304) pw[b * 2304 + j] = vals[i] * inv;
  }
}

__global__ __launch_bounds__(256) void pool1_k(const float* __restrict__ pw, const bf16* __restrict__ x,
                                               float* __restrict__ out)
{
  int b = blockIdx.y, chunk = blockIdx.x, t = threadIdx.x;
  float a0 = 0.f, a1 = 0.f;
  for (int s = 0; s < 64; s++) {
    int tok = chunk * 64 + s;
    float wv = pw[b * 2304 + tok];
    const u16* xp = (const u16*)x + ((size_t)(b * 2304 + tok)) * 512;
    a0 += wv * b2f(xp[t]);
    a1 += wv * b2f(xp[t + 256]);
  }
  atomicAdd(&out[b * 512 + t], a0);
  atomicAdd(&out[b * 512 + t + 256], a1);
}

__global__ void heads_k(const float* __restrict__ pooled,
                        const bf16* w0, const bf16* b0, const bf16* w1, const bf16* b1,
                        const bf16* w2, const bf16* b2, const bf16* w3, const bf16* b3,
                        const bf16* w4, const bf16* b4, const bf16* w5, const bf16* b5,
                        const bf16* w6, const bf16* b6, const bf16* w7, const bf16* b7,
                        void* __restrict__ outv, const int* __restrict__ flag)
{
  int idx = blockIdx.x * 256 + threadIdx.x; if (idx >= 444) return;
  const bf16* W[8] = {w0, w1, w2, w3, w4, w5, w6, w7};
  const bf16* Bi[8] = {b0, b1, b2, b3, b4, b5, b6, b7};
  int b = idx / 222, j = idx - b * 222;
  const int sizes[8]  = {48, 48, 48, 48, 8, 20, 1, 1};
  const int outoff[8] = {0, 96, 192, 288, 384, 400, 440, 442};
  int h = 0, basec = 0;
  while (h < 7 && j >= basec + sizes[h]) { basec += sizes[h]; ++h; }
  int col = j - basec;
  const bf16* wp = W[h]; int nc = sizes[h];
  float s = (float)Bi[h][col];
  for (int k = 0; k < 512; k++) s += pooled[b * 512 + k] * (float)wp[k * nc + col];
  int e = outoff[h] + b * nc + col;
  if (flag[0]) ((bf16*)outv)[e] = __float2bfloat16(s);
  else         ((float*)outv)[e] = s;
}

__global__ void outstore_k(const bf16* __restrict__ nm, void* __restrict__ outv,
                           const int* __restrict__ flag)
{
  int i = blockIdx.x * 256 + threadIdx.x; if (i >= 131072) return;
  if (flag[0]) ((bf16*)outv)[444 + i] = nm[i];
  else         ((float*)outv)[444 + i] = (float)nm[i];
}

// ---------------------------------------------------------------------------

static inline void gemm(hipStream_t st, const bf16* A, int lda, long long sAb, long long sAh,
                        const bf16* B, int ldb, long long sBb, long long sBh,
                        bf16* C, int ldc, long long sCb, long long sCh,
                        int M, int N, int K, int BZ, int HZ,
                        const bf16* bias, const bf16* res, int ldres,
                        const float* extra, int extraDiv, float alpha, int mode)
{
  dim3 g((N + 63) / 64, (M + 63) / 64, BZ * HZ);
  gemm_k<<<g, dim3(256), 0, st>>>(A, lda, sAb, sAh, B, ldb, sBb, sBh, C, ldc, sCb, sCh,
                                  M, N, K, HZ, bias, res, ldres, extra, extraDiv, alpha, mode);
}

static inline void transp(hipStream_t st, const bf16* in, bf16* out, int R, int C, int Rpad,
                          long long inB, long long outB, int Z)
{
  dim3 g((C + 31) / 32, (Rpad + 31) / 32, Z);
  transpose_k<<<g, dim3(256), 0, st>>>(in, out, R, C, Rpad, inB, outB);
}

extern "C" void kernel_launch(void* const* d_in, const int* in_sizes, int n_in,
                              void* d_out, int out_size, void* d_ws, size_t ws_size,
                              hipStream_t stream)
{
  (void)in_sizes; (void)n_in; (void)out_size;
  const int* fog = (const int*)d_in[3];

  static const int kSz[55] = {
    691200, 14, 131072, 76800, 512, 3584, 512,
    262144, 512, 262144, 512, 262144, 512, 262144, 512,
    524288, 512, 512, 512, 512, 512,
    1048576, 2048, 1048576, 2048, 1048576, 2048, 1048576, 2048,
    2048, 2048, 2048, 2048,
    4194304, 8192, 4194304, 2048,
    512, 1,
    24576, 48, 24576, 48, 24576, 48, 24576, 48,
    4096, 8, 10240, 20, 512, 1, 512, 1};
  static const int kIdx[55] = {
    0, 1, 2, 4, 5, 6, 7,
    8, 9, 10, 11, 12, 13, 14, 15,
    16, 17, 18, 19, 20, 21,
    22, 23, 24, 25, 26, 27, 28, 29,
    30, 31, 32, 33,
    34, 35, 36, 37,
    38, 39,
    40, 41, 42, 43, 44, 45, 46, 47,
    48, 49, 50, 51, 52, 53, 54, 55};

  CvtArgs ca;
  size_t cum[55]; int coffi = 0;
  for (int t = 0; t < 55; t++) {
    cum[t] = (size_t)coffi;
    ca.p[t] = d_in[kIdx[t]];
    ca.off[t] = coffi;
    ca.sz[t] = kSz[t];
    coffi += (kSz[t] + 7) & ~7;
  }
  ca.off[55] = coffi;
  size_t coff = (size_t)coffi;

  const int S = 2304, NROW = 4608, CATROW = 4864;
  const long long RS = (long long)S * 512;

  char* basep = (char*)d_ws; size_t off = 0;
  auto alloc = [&](size_t elems, size_t esz) -> void* {
    void* p = basep + off; off += (elems * esz + 255) & ~(size_t)255; return p;
  };

  bf16* canon = (bf16*)alloc(coff, 2);
  int* dflag = (int*)alloc(64, 4);
  bf16* tHex = (bf16*)alloc(512 * 160, 2);
  bf16* aPad = (bf16*)alloc((size_t)NROW * 160, 2);
  bf16* tWq = (bf16*)alloc(512 * 512, 2);
  bf16* tWk = (bf16*)alloc(512 * 512, 2);
  bf16* tWv = (bf16*)alloc(512 * 512, 2);
  bf16* tWo = (bf16*)alloc(512 * 512, 2);
  bf16* tGate = (bf16*)alloc(512 * 1024, 2);
  bf16* tLq = (bf16*)alloc(4 * 512 * 512, 2);
  bf16* tLk = (bf16*)alloc(4 * 512 * 512, 2);
  bf16* tLv = (bf16*)alloc(4 * 512 * 512, 2);
  bf16* tLo = (bf16*)alloc(4 * 512 * 512, 2);
  bf16* tF1 = (bf16*)alloc(4ULL * 2048 * 512, 2);
  bf16* tF2 = (bf16*)alloc(4ULL * 512 * 2048, 2);
  float* globF = (float*)alloc(1024, 4);
  bf16* catX = (bf16*)alloc((size_t)CATROW * 512, 2);
  bf16* Qc = (bf16*)alloc((size_t)CATROW * 512, 2);
  bf16* Kc = (bf16*)alloc((size_t)CATROW * 512, 2);
  bf16* Vc = (bf16*)alloc((size_t)CATROW * 512, 2);
  bf16* VmemT = (bf16*)alloc(16ULL * 64 * 128, 2);
  bf16* VsT = (bf16*)alloc(16ULL * 64 * S, 2);
  bf16* mo = (bf16*)alloc((size_t)NROW * 512, 2);
  bf16* tmp1 = (bf16*)alloc((size_t)NROW * 512, 2);
  bf16* xbuf = (bf16*)alloc((size_t)NROW * 512, 2);
  bf16* x2buf = (bf16*)alloc((size_t)NROW * 512, 2);
  bf16* mu0 = (bf16*)alloc(256 * 512, 2);
  bf16* mup = (bf16*)alloc(256 * 512, 2);
  bf16* catg = (bf16*)alloc(256 * 1024, 2);
  bf16* gateb = (bf16*)alloc(256 * 512, 2);
  bf16* nmpre = (bf16*)alloc(256 * 512, 2);
  bf16* nmout = (bf16*)alloc(256 * 512, 2);
  float* plog = (float*)alloc(NROW, 4);
  float* pwv = (float*)alloc(NROW, 4);
  float* pooledF = (float*)alloc(1024, 4);
  float* oAcc = (float*)alloc((size_t)NROW * 512, 4);
  float* lAcc = (float*)alloc(16 * 2304, 4);
  bf16* hbuf = (bf16*)alloc((size_t)NROW * 2048, 2);
  if (off > ws_size) return;

  detect_k<<<1, 512, 0, stream>>>((const unsigned int*)d_in[0], dflag);
  cvtall8_k<<<(coffi / 8 + 255) / 256, 256, 0, stream>>>(ca, canon, dflag);

  auto T = [&](int t) -> const bf16* { return canon + cum[t]; };
  const bf16* map_rep = T(0);
  const bf16* gfeat   = T(1);
  const bf16* memin   = T(2);
  const bf16* hex_w = T(3);  const bf16* hex_b = T(4);
  const bf16* glob_w = T(5); const bf16* glob_b = T(6);
  const bf16* mem_wq = T(7);  const bf16* mem_bq = T(8);
  const bf16* mem_wk = T(9);  const bf16* mem_bk = T(10);
  const bf16* mem_wv = T(11); const bf16* mem_bv = T(12);
  const bf16* mem_wo = T(13); const bf16* mem_bo = T(14);
  const bf16* gate_w = T(15); const bf16* gate_b = T(16);
  const bf16* mn1_g = T(17); const bf16* mn1_b = T(18);
  const bf16* mn2_g = T(19); const bf16* mn2_b = T(20);
  const bf16* lw_q = T(21); const bf16* lb_q = T(22);
  const bf16* lw_k = T(23); const bf16* lb_k = T(24);
  const bf16* lw_v = T(25); const bf16* lb_v = T(26);
  const bf16* lw_o = T(27); const bf16* lb_o = T(28);
  const bf16* ln1_g = T(29); const bf16* ln1_b = T(30);
  const bf16* ln2_g = T(31); const bf16* ln2_b = T(32);
  const bf16* ff1_w = T(33); const bf16* ff1_b = T(34);
  const bf16* ff2_w = T(35); const bf16* ff2_b = T(36);
  const bf16* pool_w = T(37); const bf16* pool_b = T(38);

  // ---- weight transposes ----
  transp(stream, hex_w, tHex, 150, 512, 160, 0, 0, 1);
  transp(stream, mem_wq, tWq, 512, 512, 512, 0, 0, 1);
  transp(stream, mem_wk, tWk, 512, 512, 512, 0, 0, 1);
  transp(stream, mem_wv, tWv, 512, 512, 512, 0, 0, 1);
  transp(stream, mem_wo, tWo, 512, 512, 512, 0, 0, 1);
  transp(stream, gate_w, tGate, 1024, 512, 1024, 0, 0, 1);
  transp(stream, lw_q, tLq, 512, 512, 512, 262144, 262144, 4);
  transp(stream, lw_k, tLk, 512, 512, 512, 262144, 262144, 4);
  transp(stream, lw_v, tLv, 512, 512, 512, 262144, 262144, 4);
  transp(stream, lw_o, tLo, 512, 512, 512, 262144, 262144, 4);
  transp(stream, ff1_w, tF1, 512, 2048, 512, 1048576, 1048576, 4);
  transp(stream, ff2_w, tF2, 2048, 512, 2048, 1048576, 1048576, 4);

  // ---- seq = map@hex_w + hex_b + glob ----
  glob_k<<<4, 256, 0, stream>>>(gfeat, glob_w, glob_b, globF);
  padA_k<<<(NROW * 160 + 255) / 256, 256, 0, stream>>>(map_rep, aPad);
  gemm(stream, aPad, 160, 0, 0, tHex, 160, 0, 0, catX, 512, 0, 0,
       NROW, 512, 160, 1, 1, hex_b, nullptr, 0, globF, S, 1.f, 1);
  hipMemcpyAsync(catX + (size_t)NROW * 512, memin, 256 * 512 * 2, hipMemcpyDeviceToDevice, stream);

  // ---- shared-weight Q/K/V over [seq ; memory] ----
  gemm(stream, catX, 512, 0, 0, tWq, 512, 0, 0, Qc, 512, 0, 0, CATROW, 512, 512, 1, 1, mem_bq, nullptr, 0, nullptr, 1, 1.f, 0);
  gemm(stream, catX, 512, 0, 0, tWk, 512, 0, 0, Kc, 512, 0, 0, CATROW, 512, 512, 1, 1, mem_bk, nullptr, 0, nullptr, 1, 1.f, 0);
  gemm(stream, catX, 512, 0, 0, tWv, 512, 0, 0, Vc, 512, 0, 0, CATROW, 512, 512, 1, 1, mem_bv, nullptr, 0, nullptr, 1, 1.f, 0);

  // ---- mem_out = MHA(seq, memory, memory), flash ----
  headT_k<<<dim3(4, 2, 16), 256, 0, stream>>>(Vc, VmemT, 128, NROW, 128);
  hipMemsetAsync(oAcc, 0, (size_t)NROW * 512 * 4, stream);
  hipMemsetAsync(lAcc, 0, 16 * 2304 * 4, stream);
  flash_k<<<dim3(36, 16, 1), 256, 0, stream>>>(Qc, RS, Kc + (size_t)NROW * 512, 128 * 512,
                                               VmemT, 64 * 128, oAcc, RS, lAcc, 2304,
                                               nullptr, 2, 128);
  fdiv4_k<<<(NROW * 128 + 255) / 256, 256, 0, stream>>>(oAcc, lAcc, 2304, 2304, NROW, mo);
  gemm(stream, mo, 512, 0, 0, tWo, 512, 0, 0, tmp1, 512, 0, 0,
       NROW, 512, 512, 1, 1, mem_bo, catX, 512, nullptr, 1, 1.f, 4);
  ln_k<<<NROW / 4, 256, 0, stream>>>(tmp1, mn1_g, mn1_b, xbuf);

  // ---- mem_upd = MHA(memory, seq, seq), flash split-K + gated update ----
  headT_k<<<dim3(72, 2, 16), 256, 0, stream>>>(Vc, VsT, S, 0, S);
  hipMemsetAsync(oAcc, 0, 256 * 512 * 4, stream);
  hipMemsetAsync(lAcc, 0, 16 * 128 * 4, stream);
  flash_k<<<dim3(2, 16, 6), 256, 0, stream>>>(Qc + (size_t)NROW * 512, 128 * 512, Kc, RS,
                                              VsT, 64LL * S, oAcc, 128 * 512, lAcc, 128,
                                              nullptr, 6, S);
  fdiv4_k<<<(256 * 128 + 255) / 256, 256, 0, stream>>>(oAcc, lAcc, 128, 128, 256, mu0);
  gemm(stream, mu0, 512, 0, 0, tWo, 512, 0, 0, mup, 512, 0, 0,
       256, 512, 512, 1, 1, mem_bo, nullptr, 0, nullptr, 1, 1.f, 0);
  catg_k<<<(256 * 1024 + 255) / 256, 256, 0, stream>>>(memin, mup, catg);
  gemm(stream, catg, 1024, 0, 0, tGate, 1024, 0, 0, gateb, 512, 0, 0,
       256, 512, 1024, 1, 1, gate_b, nullptr, 0, nullptr, 1, 1.f, 5);
  gcomb_k<<<(131072 + 255) / 256, 256, 0, stream>>>(gateb, mup, memin, nmpre);
  ln_k<<<64, 256, 0, stream>>>(nmpre, mn2_g, mn2_b, nmout);
  outstore_k<<<(131072 + 255) / 256, 256, 0, stream>>>(nmout, d_out, dflag);

  // ---- transformer layers ----
  for (int l = 0; l < 4; l++) {
    gemm(stream, xbuf, 512, 0, 0, tLq + (size_t)l * 262144, 512, 0, 0, Qc, 512, 0, 0,
         NROW, 512, 512, 1, 1, lb_q + l * 512, nullptr, 0, nullptr, 1, 1.f, 0);
    gemm(stream, xbuf, 512, 0, 0, tLk + (size_t)l * 262144, 512, 0, 0, Kc, 512, 0, 0,
         NROW, 512, 512, 1, 1, lb_k + l * 512, nullptr, 0, nullptr, 1, 1.f, 0);
    gemm(stream, xbuf, 512, 0, 0, tLv + (size_t)l * 262144, 512, 0, 0, Vc, 512, 0, 0,
         NROW, 512, 512, 1, 1, lb_v + l * 512, nullptr, 0, nullptr, 1, 1.f, 0);
    headT_k<<<dim3(72, 2, 16), 256, 0, stream>>>(Vc, VsT, S, 0, S);
    hipMemsetAsync(oAcc, 0, (size_t)NROW * 512 * 4, stream);
    hipMemsetAsync(lAcc, 0, 16 * 2304 * 4, stream);
    flash_k<<<dim3(36, 16, 2), 256, 0, stream>>>(Qc, RS, Kc, RS, VsT, 64LL * S,
                                                 oAcc, RS, lAcc, 2304, fog, 18, S);
    fdiv4_k<<<(NROW * 128 + 255) / 256, 256, 0, stream>>>(oAcc, lAcc, 2304, 2304, NROW, mo);
    gemm(stream, mo, 512, 0, 0, tLo + (size_t)l * 262144, 512, 0, 0, tmp1, 512, 0, 0,
         NROW, 512, 512, 1, 1, lb_o + l * 512, xbuf, 512, nullptr, 1, 1.f, 4);
    ln_k<<<NROW / 4, 256, 0, stream>>>(tmp1, ln1_g + l * 512, ln1_b + l * 512, x2buf);
    {
      dim3 g(2048 / 128, NROW / 128);
      gemm128p_k<<<g, dim3(256), 0, stream>>>(x2buf, 512, tF1 + (size_t)l * 1048576, 512,
                                              hbuf, 2048, 512, ff1_b + l * 2048,
                                              nullptr, 0, nullptr, 1, 1.f, 2);
    }
    gemm(stream, hbuf, 2048, 0, 0, tF2 + (size_t)l * 1048576, 2048, 0, 0, tmp1, 512, 0, 0,
         NROW, 512, 2048, 1, 1, ff2_b + l * 512, x2buf, 512, nullptr, 1, 1.f, 4);
    ln_k<<<NROW / 4, 256, 0, stream>>>(tmp1, ln2_g + l * 512, ln2_b + l * 512, xbuf);
  }

  // ---- attention pooling + heads ----
  plog_k<<<NROW, 64, 0, stream>>>(xbuf, pool_w, pool_b, plog);
  psm_k<<<2, 256, 0, stream>>>(plog, pwv);
  hipMemsetAsync(pooledF, 0, 1024 * sizeof(float), stream);
  pool1_k<<<dim3(36, 2), 256, 0, stream>>>(pwv, xbuf, pooledF);

  heads_k<<<2, 256, 0, stream>>>(pooledF,
      T(39), T(40), T(41), T(42), T(43), T(44), T(45), T(46),
      T(47), T(48), T(49), T(50), T(51), T(52), T(53), T(54),
      d_out, dflag);
}

// Round 9
// 1184.281 us; speedup vs baseline: 1.0752x; 1.0752x over previous
//
#include <hip/hip_runtime.h>
#include <hip/hip_bf16.h>

typedef __hip_bfloat16 bf16;
typedef unsigned short u16;
typedef __attribute__((ext_vector_type(8))) short short8;
typedef __attribute__((ext_vector_type(4))) float f32x4;

__device__ inline float b2f(u16 u){ unsigned int x = ((unsigned int)u) << 16; float f; __builtin_memcpy(&f, &x, 4); return f; }
__device__ inline u16 f2bits(float f){ __hip_bfloat16 h = __float2bfloat16(f); u16 u; __builtin_memcpy(&u, &h, 2); return u; }
__device__ inline void unpk(unsigned int w, float& a, float& b){ a = b2f((u16)(w & 0xffffu)); b = b2f((u16)(w >> 16)); }

// pack two fp32 -> bf16x2 (round via +0x8000, then byte-perm) [verified r7]
__device__ __forceinline__ unsigned int pkbf(float a, float b)
{
  unsigned int ua = __float_as_uint(a) + 0x8000u;
  unsigned int ub = __float_as_uint(b) + 0x8000u;
  return __builtin_amdgcn_perm(ub, ua, 0x07060302u);
}

// ---------------------------------------------------------------------------
// dtype detection (verified round 2)
// ---------------------------------------------------------------------------
__global__ __launch_bounds__(512) void detect_k(const unsigned int* __restrict__ raw, int* __restrict__ flag)
{
  __shared__ int cnt;
  if (threadIdx.x == 0) cnt = 0;
  __syncthreads();
  unsigned int w = raw[threadIdx.x];
  unsigned int b = w & 0x7fffu;
  int pat = (b >= 0x2000u && b <= 0x4400u) ? 1 : 0;
#pragma unroll
  for (int o = 32; o; o >>= 1) pat += __shfl_xor(pat, o);
  if ((threadIdx.x & 63) == 0) atomicAdd(&cnt, pat);
  __syncthreads();
  if (threadIdx.x == 0) flag[0] = (cnt > 320) ? 1 : 0;
}

struct CvtArgs { const void* p[55]; int off[56]; int sz[55]; };

// vectorized x8 conversion (verified round 5)
__global__ __launch_bounds__(256) void cvtall8_k(CvtArgs a, bf16* __restrict__ dst,
                                                 const int* __restrict__ flag)
{
  int g8 = blockIdx.x * 256 + threadIdx.x;
  int gid = g8 * 8;
  if (gid >= a.off[55]) return;
  int lo = 0, hi = 54;
  while (lo < hi) { int mid = (lo + hi + 1) >> 1; if (gid >= a.off[mid]) lo = mid; else hi = mid - 1; }
  int t = lo, i = gid - a.off[t];
  int n = a.sz[t];
  uint4 ov;
  if (flag[0]) {
    const u16* src = (const u16*)a.p[t];
    if (i + 8 <= n) {
      ov = *(const uint4*)(src + i);
    } else {
      u16 tmp[8];
#pragma unroll
      for (int j = 0; j < 8; j++) tmp[j] = (i + j < n) ? src[i + j] : (u16)0;
      __builtin_memcpy(&ov, tmp, 16);
    }
  } else {
    const float* src = (const float*)a.p[t];
    float v[8];
    if (i + 8 <= n) {
      uint4 f0 = *(const uint4*)(src + i);
      uint4 f1 = *(const uint4*)(src + i + 4);
      __builtin_memcpy(&v[0], &f0, 16);
      __builtin_memcpy(&v[4], &f1, 16);
    } else {
#pragma unroll
      for (int j = 0; j < 8; j++) v[j] = (i + j < n) ? src[i + j] : 0.f;
    }
    u16 o8[8];
#pragma unroll
    for (int j = 0; j < 8; j++) o8[j] = f2bits(v[j]);
    __builtin_memcpy(&ov, o8, 16);
  }
  *(uint4*)((u16*)dst + gid) = ov;
}

// ---------------------------------------------------------------------------
// 64-tile GEMM (verified r2) + register prefetch (verified r6)
// mode: 0 plain(+bias), 1 +bias+extra, 2 gelu(+bias), 3 scale, 4 +bias+res, 5 sigmoid
// ---------------------------------------------------------------------------
__global__ __launch_bounds__(256) void gemm_k(
    const bf16* __restrict__ A, int lda, long long sAb, long long sAh,
    const bf16* __restrict__ B, int ldb, long long sBb, long long sBh,
    bf16* __restrict__ C, int ldc, long long sCb, long long sCh,
    int M, int N, int K, int HZ,
    const bf16* __restrict__ bias,
    const bf16* __restrict__ res, int ldres,
    const float* __restrict__ extra, int extraDiv,
    float alpha, int mode)
{
  __shared__ u16 As[64][40];
  __shared__ u16 Bs[64][40];
  int z = blockIdx.z;
  int bz = z / HZ, hz = z - bz * HZ;
  A += (size_t)bz * sAb + (size_t)hz * sAh;
  B += (size_t)bz * sBb + (size_t)hz * sBh;
  C += (size_t)bz * sCb + (size_t)hz * sCh;

  int m0 = blockIdx.y * 64, n0 = blockIdx.x * 64;
  int t = threadIdx.x;
  int r = t >> 2, c0 = (t & 3) << 3;
  int lane = t & 63, wv = t >> 6, lr = lane & 15, lq = lane >> 4;

  f32x4 acc[4];
#pragma unroll
  for (int i = 0; i < 4; i++) acc[i] = (f32x4){0.f, 0.f, 0.f, 0.f};

  const u16* Ag = (const u16*)A;
  const u16* Bg = (const u16*)B;
  bool aok = (m0 + r < M), bok = (n0 + r < N);
  const u16* arow = Ag + (size_t)(m0 + r) * lda + c0;
  const u16* brow = Bg + (size_t)(n0 + r) * ldb + c0;

  uint4 av = {0u,0u,0u,0u}, bv = {0u,0u,0u,0u};
  if (aok) av = *(const uint4*)(arow);
  if (bok) bv = *(const uint4*)(brow);

  for (int kt = 0; kt < K; kt += 32) {
    __syncthreads();
    *(uint4*)&As[r][c0] = av;
    *(uint4*)&Bs[r][c0] = bv;
    uint4 av2 = {0u,0u,0u,0u}, bv2 = {0u,0u,0u,0u};
    int nk = kt + 32;
    if (nk < K) {
      if (aok) av2 = *(const uint4*)(arow + nk);
      if (bok) bv2 = *(const uint4*)(brow + nk);
    }
    __syncthreads();
    short8 af = *(const short8*)&As[wv * 16 + lr][lq * 8];
#pragma unroll
    for (int nt = 0; nt < 4; nt++) {
      short8 bfr = *(const short8*)&Bs[nt * 16 + lr][lq * 8];
      acc[nt] = __builtin_amdgcn_mfma_f32_16x16x32_bf16(af, bfr, acc[nt], 0, 0, 0);
    }
    av = av2; bv = bv2;
  }

#pragma unroll
  for (int nt = 0; nt < 4; nt++) {
    int nn = n0 + nt * 16 + lr;
    if (nn >= N) continue;
    float bb = bias ? (float)bias[nn] : 0.f;
#pragma unroll
    for (int rr = 0; rr < 4; rr++) {
      int mm = m0 + wv * 16 + lq * 4 + rr;
      if (mm >= M) continue;
      float v = acc[nt][rr] * alpha + bb;
      if (mode == 1)      v += extra[(mm / extraDiv) * 512 + nn];
      else if (mode == 2) v = 0.5f * v * (1.f + erff(v * 0.70710678118654752f));
      else if (mode == 4) v += (float)res[(size_t)mm * ldres + nn];
      else if (mode == 5) v = 1.f / (1.f + expf(-v));
      C[(size_t)mm * ldc + nn] = __float2bfloat16(v);
    }
  }
}

// ---------------------------------------------------------------------------
// Flash v5: fixed-max split-K + XOR-swizzle (r7) + mask-AND + ones-MFMA l (r8)
// + register-prefetched K/V staging (r6 gemm pattern): next tile's global
// loads issued during current tile's compute, hiding global latency.
// ---------------------------------------------------------------------------
__device__ __forceinline__ int swz(int row, int cg)
{
  return row * 64 + ((cg ^ (row & 3) ^ (((row >> 3) & 1) << 2)) << 3);
}

__global__ __launch_bounds__(256) void flash_k(
    const bf16* __restrict__ Qp, long long sQb,
    const bf16* __restrict__ Kp, long long sKb,
    const bf16* __restrict__ VTp, long long sVz,
    float* __restrict__ oAcc, long long sOb,
    float* __restrict__ lAcc, int Ml,
    const int* __restrict__ fog,
    int tilesPerSplit, int SkLen)
{
  __shared__ u16 Kl[64 * 64];
  __shared__ u16 Vl[64 * 64];
  __shared__ u16 fgl16[2304];

  const float SC = 0.125f * 1.44269504088896340736f;
  int z = blockIdx.y, b = z >> 3, h = z & 7;
  int qt = blockIdx.x;
  int kt0 = blockIdx.z * tilesPerSplit;
  int t = threadIdx.x, lane = t & 63, w = t >> 6;
  int lr = lane & 15, lq = lane >> 4;
  int useMask = (fog != nullptr);

  const u16* Qg = (const u16*)Qp + (size_t)b * sQb + h * 64;
  const u16* Kg = (const u16*)Kp + (size_t)b * sKb + h * 64;
  const u16* Vg = (const u16*)VTp + (size_t)z * sVz;

  if (useMask) {
    for (int j = t; j < SkLen; j += 256) fgl16[j] = fog[b * 2304 + j] ? 0xFFFFu : 0u;
  }

  int qrow = qt * 64 + w * 16 + lr;
  short8 qf0, qf1;
  {
    union { short8 s; u16 u[8]; } i0, i1, o0, o1;
    i0.s = *(const short8*)(Qg + (size_t)qrow * 512 + lq * 8);
    i1.s = *(const short8*)(Qg + (size_t)qrow * 512 + 32 + lq * 8);
#pragma unroll
    for (int j = 0; j < 8; j++) {
      o0.u[j] = f2bits(b2f(i0.u[j]) * SC);
      o1.u[j] = f2bits(b2f(i1.u[j]) * SC);
    }
    qf0 = o0.s; qf1 = o1.s;
  }

  short8 ones8;
  {
    union { short8 s; u16 u[8]; } on;
#pragma unroll
    for (int j = 0; j < 8; j++) on.u[j] = 0x3F80u;
    ones8 = on.s;
  }

  int rowA[4], kAd0[4], kAd1[4];
#pragma unroll
  for (int nt = 0; nt < 4; nt++) {
    rowA[nt] = 32 * (nt >> 1) + 8 * (lr >> 2) + 4 * (nt & 1) + (lr & 3);
    kAd0[nt] = swz(rowA[nt], lq);
    kAd1[nt] = swz(rowA[nt], lq + 4);
  }
  int vAd0[4], vAd1[4];
#pragma unroll
  for (int dt = 0; dt < 4; dt++) {
    vAd0[dt] = swz(dt * 16 + lr, lq);
    vAd1[dt] = swz(dt * 16 + lr, lq + 4);
  }

  f32x4 o[4], ol;
#pragma unroll
  for (int i = 0; i < 4; i++) o[i] = (f32x4){0.f, 0.f, 0.f, 0.f};
  ol = (f32x4){0.f, 0.f, 0.f, 0.f};

  int rr = t >> 2, cg = t & 3, cs = cg * 8;
  int wAd0 = swz(rr, cg), wAd1 = swz(rr, cg + 4);

  const u16* krow = Kg + (size_t)(kt0 * 64 + rr) * 512 + cs;
  const u16* vrow = Vg + (size_t)rr * SkLen + kt0 * 64 + cs;
  uint4 ka = *(const uint4*)(krow);
  uint4 kb = *(const uint4*)(krow + 32);
  uint4 va = *(const uint4*)(vrow);
  uint4 vb = *(const uint4*)(vrow + 32);

  for (int kti = 0; kti < tilesPerSplit; kti++) {
    int kt = kt0 + kti;
    __syncthreads();
    *(uint4*)&Kl[wAd0] = ka;
    *(uint4*)&Kl[wAd1] = kb;
    *(uint4*)&Vl[wAd0] = va;
    *(uint4*)&Vl[wAd1] = vb;
    if (kti + 1 < tilesPerSplit) {
      krow += 64 * 512;
      vrow += 64;
      ka = *(const uint4*)(krow);
      kb = *(const uint4*)(krow + 32);
      va = *(const uint4*)(vrow);
      vb = *(const uint4*)(vrow + 32);
    }
    __syncthreads();

    f32x4 s[4];
#pragma unroll
    for (int nt = 0; nt < 4; nt++) {
      s[nt] = (f32x4){0.f, 0.f, 0.f, 0.f};
      short8 kf0 = *(const short8*)&Kl[kAd0[nt]];
      short8 kf1 = *(const short8*)&Kl[kAd1[nt]];
      s[nt] = __builtin_amdgcn_mfma_f32_16x16x32_bf16(kf0, qf0, s[nt], 0, 0, 0);
      s[nt] = __builtin_amdgcn_mfma_f32_16x16x32_bf16(kf1, qf1, s[nt], 0, 0, 0);
    }

    union { unsigned int u[4]; short8 s8; } pk0, pk1;
#pragma unroll
    for (int nt = 0; nt < 4; nt++) {
      float p0 = exp2f(s[nt][0]), p1 = exp2f(s[nt][1]);
      float p2 = exp2f(s[nt][2]), p3 = exp2f(s[nt][3]);
      unsigned int w0 = pkbf(p0, p1);
      unsigned int w1 = pkbf(p2, p3);
      if (useMask) {
        int key = kt * 64 + 32 * (nt >> 1) + 8 * lq + 4 * (nt & 1);
        uint2 mm = *(const uint2*)&fgl16[key];
        w0 &= mm.x; w1 &= mm.y;
      }
      if (nt < 2) { pk0.u[(nt & 1) * 2] = w0; pk0.u[(nt & 1) * 2 + 1] = w1; }
      else        { pk1.u[(nt & 1) * 2] = w0; pk1.u[(nt & 1) * 2 + 1] = w1; }
    }
#pragma unroll
    for (int dt = 0; dt < 4; dt++) {
      short8 vf0 = *(const short8*)&Vl[vAd0[dt]];
      short8 vf1 = *(const short8*)&Vl[vAd1[dt]];
      o[dt] = __builtin_amdgcn_mfma_f32_16x16x32_bf16(pk0.s8, vf0, o[dt], 0, 0, 0);
      o[dt] = __builtin_amdgcn_mfma_f32_16x16x32_bf16(pk1.s8, vf1, o[dt], 0, 0, 0);
    }
    ol = __builtin_amdgcn_mfma_f32_16x16x32_bf16(pk0.s8, ones8, ol, 0, 0, 0);
    ol = __builtin_amdgcn_mfma_f32_16x16x32_bf16(pk1.s8, ones8, ol, 0, 0, 0);
  }

  if (lr == 0) {
#pragma unroll
    for (int r2 = 0; r2 < 4; r2++)
      atomicAdd(&lAcc[z * Ml + qt * 64 + w * 16 + lq * 4 + r2], ol[r2]);
  }

  float* ob = oAcc + (size_t)b * sOb;
  int qb = qt * 64 + w * 16 + lq * 4;
#pragma unroll
  for (int dt = 0; dt < 4; dt++)
#pragma unroll
    for (int r2 = 0; r2 < 4; r2++)
      atomicAdd(&ob[(size_t)(qb + r2) * 512 + h * 64 + dt * 16 + lr], o[dt][r2]);
}

// normalize, vectorized x4
__global__ __launch_bounds__(256) void fdiv4_k(const float* __restrict__ oAcc,
                                               const float* __restrict__ lAcc,
                                               int Mq, int Ml, int rows,
                                               bf16* __restrict__ out)
{
  int i = (blockIdx.x * 256 + threadIdx.x) * 4;
  if (i >= rows * 512) return;
  int row = i >> 9, col = i & 511;
  int b = row / Mq, q = row - b * Mq;
  int zz = b * 8 + (col >> 6);
  float l = lAcc[zz * Ml + q];
  float inv = (l > 0.f) ? 1.f / l : 0.f;
  float4 v = *(const float4*)(oAcc + i);
  u16 o4[4] = {f2bits(v.x * inv), f2bits(v.y * inv), f2bits(v.z * inv), f2bits(v.w * inv)};
  unsigned int lo = o4[0] | ((unsigned)o4[1] << 16);
  unsigned int hi = o4[2] | ((unsigned)o4[3] << 16);
  *(uint2*)((u16*)out + i) = (uint2){lo, hi};
}

// in [R,C] row-major -> out [C,Rpad], zero-filled for src rows >= R
__global__ __launch_bounds__(256) void transpose_k(const bf16* __restrict__ in, bf16* __restrict__ out,
                                                   int R, int C, int Rpad, long long inB, long long outB)
{
  __shared__ u16 tile[32][33];
  const u16* ip = (const u16*)in + (size_t)blockIdx.z * inB;
  u16* op = (u16*)out + (size_t)blockIdx.z * outB;
  int c0 = blockIdx.x * 32, r0 = blockIdx.y * 32;
  int tx = threadIdx.x & 31, ty = threadIdx.x >> 5;
#pragma unroll
  for (int j = 0; j < 4; j++) {
    int rr = r0 + ty + j * 8, cc = c0 + tx;
    u16 v = 0;
    if (rr < R && cc < C) v = ip[(size_t)rr * C + cc];
    tile[ty + j * 8][tx] = v;
  }
  __syncthreads();
#pragma unroll
  for (int j = 0; j < 4; j++) {
    int oc = c0 + ty + j * 8;
    if (oc < C && r0 + tx < Rpad) op[(size_t)oc * Rpad + r0 + tx] = tile[tx][ty + j * 8];
  }
}

__global__ __launch_bounds__(256) void headT_k(const bf16* __restrict__ in, bf16* __restrict__ out,
                                               int Sk, int rowbase, int bstride)
{
  __shared__ u16 tile[32][33];
  int z = blockIdx.z, b = z >> 3, h = z & 7;
  const u16* ip = (const u16*)in + ((size_t)(rowbase + b * bstride)) * 512 + h * 64;
  u16* op = (u16*)out + (size_t)z * 64 * Sk;
  int r0 = blockIdx.x * 32, c0 = blockIdx.y * 32;
  int tx = threadIdx.x & 31, ty = threadIdx.x >> 5;
#pragma unroll
  for (int j = 0; j < 4; j++)
    tile[ty + j * 8][tx] = ip[(size_t)(r0 + ty + j * 8) * 512 + c0 + tx];
  __syncthreads();
#pragma unroll
  for (int j = 0; j < 4; j++)
    op[(size_t)(c0 + ty + j * 8) * Sk + r0 + tx] = tile[tx][ty + j * 8];
}

// row LayerNorm over D=512, 4 rows/block (wave per row)
__global__ __launch_bounds__(256) void ln_k(const bf16* __restrict__ in, const bf16* __restrict__ g,
                                            const bf16* __restrict__ bb, bf16* __restrict__ out)
{
  size_t row = blockIdx.x * 4 + (threadIdx.x >> 6);
  int lane = threadIdx.x & 63;
  const u16* ip = (const u16*)in + row * 512 + lane * 8;
  uint4 rv = *(const uint4*)ip;
  float v[8];
  unpk(rv.x, v[0], v[1]); unpk(rv.y, v[2], v[3]); unpk(rv.z, v[4], v[5]); unpk(rv.w, v[6], v[7]);
  float s = 0.f, s2 = 0.f;
#pragma unroll
  for (int k = 0; k < 8; k++) { s += v[k]; s2 += v[k] * v[k]; }
#pragma unroll
  for (int o = 32; o; o >>= 1) { s += __shfl_xor(s, o); s2 += __shfl_xor(s2, o); }
  float mean = s * (1.f / 512.f);
  float var = s2 * (1.f / 512.f) - mean * mean;
  float rstd = rsqrtf(var + 1e-5f);
  uint4 gv = *(const uint4*)((const u16*)g + lane * 8);
  uint4 bv = *(const uint4*)((const u16*)bb + lane * 8);
  float gf[8], bf2[8];
  unpk(gv.x, gf[0], gf[1]); unpk(gv.y, gf[2], gf[3]); unpk(gv.z, gf[4], gf[5]); unpk(gv.w, gf[6], gf[7]);
  unpk(bv.x, bf2[0], bf2[1]); unpk(bv.y, bf2[2], bf2[3]); unpk(bv.z, bf2[4], bf2[5]); unpk(bv.w, bf2[6], bf2[7]);
  u16 o8[8];
#pragma unroll
  for (int k = 0; k < 8; k++) o8[k] = f2bits((v[k] - mean) * rstd * gf[k] + bf2[k]);
  uint4 ov;
  ov.x = o8[0] | ((unsigned)o8[1] << 16); ov.y = o8[2] | ((unsigned)o8[3] << 16);
  ov.z = o8[4] | ((unsigned)o8[5] << 16); ov.w = o8[6] | ((unsigned)o8[7] << 16);
  *(uint4*)((u16*)out + row * 512 + lane * 8) = ov;
}

__global__ void glob_k(const bf16* __restrict__ gf, const bf16* __restrict__ gw,
                       const bf16* __restrict__ gb, float* __restrict__ out)
{
  int i = blockIdx.x * 256 + threadIdx.x; if (i >= 1024) return;
  int b = i >> 9, d = i & 511;
  float s = (float)gb[d];
#pragma unroll
  for (int f = 0; f < 7; f++) s += (float)gf[b * 7 + f] * (float)gw[f * 512 + d];
  out[i] = s;
}

__global__ void padA_k(const bf16* __restrict__ in, bf16* __restrict__ out)
{
  int i = blockIdx.x * 256 + threadIdx.x; if (i >= 4608 * 160) return;
  int r = i / 160, c = i - r * 160;
  out[i] = (c < 150) ? in[r * 150 + c] : __float2bfloat16(0.f);
}

__global__ void catg_k(const bf16* __restrict__ mem, const bf16* __restrict__ mu, bf16* __restrict__ out)
{
  int i = blockIdx.x * 256 + threadIdx.x; if (i >= 256 * 1024) return;
  int r = i >> 10, c = i & 1023;
  out[i] = (c < 512) ? mem[r * 512 + c] : mu[r * 512 + c - 512];
}

__global__ void gcomb_k(const bf16* __restrict__ g, const bf16* __restrict__ mu,
                        const bf16* __restrict__ mem, bf16* __restrict__ out)
{
  int i = blockIdx.x * 256 + threadIdx.x; if (i >= 131072) return;
  float gg = (float)g[i];
  out[i] = __float2bfloat16(gg * (float)mu[i] + (1.f - gg) * (float)mem[i]);
}

__global__ __launch_bounds__(64) void plog_k(const bf16* __restrict__ x, const bf16* __restrict__ pw,
                                             const bf16* __restrict__ pb, float* __restrict__ out)
{
  size_t row = blockIdx.x; int lane = threadIdx.x;
  uint4 xv = *(const uint4*)((const u16*)x + row * 512 + lane * 8);
  uint4 wv = *(const uint4*)((const u16*)pw + lane * 8);
  float v[8], w[8];
  unpk(xv.x, v[0], v[1]); unpk(xv.y, v[2], v[3]); unpk(xv.z, v[4], v[5]); unpk(xv.w, v[6], v[7]);
  unpk(wv.x, w[0], w[1]); unpk(wv.y, w[2], w[3]); unpk(wv.z, w[4], w[5]); unpk(wv.w, w[6], w[7]);
  float s = 0.f;
#pragma unroll
  for (int k = 0; k < 8; k++) s += v[k] * w[k];
#pragma unroll
  for (int o = 32; o; o >>= 1) s += __shfl_xor(s, o);
  if (lane == 0) out[row] = s + (float)pb[0];
}

__global__ __launch_bounds__(256) void psm_k(const float* __restrict__ lg, float* __restrict__ pw)
{
  __shared__ float red[4];
  int b = blockIdx.x, tid = threadIdx.x;
  const float* p = lg + b * 2304;
  float vals[9]; float mx = -3e38f;
#pragma unroll
  for (int i = 0; i < 9; i++) {
    int j = tid + i * 256;
    float x = (j < 2304) ? p[j] : -3e38f;
    vals[i] = x; mx = fmaxf(mx, x);
  }
#pragma unroll
  for (int o = 32; o; o >>= 1) mx = fmaxf(mx, __shfl_xor(mx, o));
  if ((tid & 63) == 0) red[tid >> 6] = mx;
  __syncthreads();
  mx = fmaxf(fmaxf(red[0], red[1]), fmaxf(red[2], red[3]));
  float sum = 0.f;
#pragma unroll
  for (int i = 0; i < 9; i++) {
    int j = tid + i * 256;
    if (j < 2304) { float e = expf(vals[i] - mx); vals[i] = e; sum += e; }
  }
  __syncthreads();
#pragma unroll
  for (int o = 32; o; o >>= 1) sum += __shfl_xor(sum, o);
  if ((tid & 63) == 0) red[tid >> 6] = sum;
  __syncthreads();
  sum = red[0] + red[1] + red[2] + red[3];
  float inv = 1.f / sum;
#pragma unroll
  for (int i = 0; i < 9; i++) {
    int j = tid + i * 256;
    if (j < 2304) pw[b * 2304 + j] = vals[i] * inv;
  }
}

__global__ __launch_bounds__(256) void pool1_k(const float* __restrict__ pw, const bf16* __restrict__ x,
                                               float* __restrict__ out)
{
  int b = blockIdx.y, chunk = blockIdx.x, t = threadIdx.x;
  float a0 = 0.f, a1 = 0.f;
  for (int s = 0; s < 64; s++) {
    int tok = chunk * 64 + s;
    float wv = pw[b * 2304 + tok];
    const u16* xp = (const u16*)x + ((size_t)(b * 2304 + tok)) * 512;
    a0 += wv * b2f(xp[t]);
    a1 += wv * b2f(xp[t + 256]);
  }
  atomicAdd(&out[b * 512 + t], a0);
  atomicAdd(&out[b * 512 + t + 256], a1);
}

__global__ void heads_k(const float* __restrict__ pooled,
                        const bf16* w0, const bf16* b0, const bf16* w1, const bf16* b1,
                        const bf16* w2, const bf16* b2, const bf16* w3, const bf16* b3,
                        const bf16* w4, const bf16* b4, const bf16* w5, const bf16* b5,
                        const bf16* w6, const bf16* b6, const bf16* w7, const bf16* b7,
                        void* __restrict__ outv, const int* __restrict__ flag)
{
  int idx = blockIdx.x * 256 + threadIdx.x; if (idx >= 444) return;
  const bf16* W[8] = {w0, w1, w2, w3, w4, w5, w6, w7};
  const bf16* Bi[8] = {b0, b1, b2, b3, b4, b5, b6, b7};
  int b = idx / 222, j = idx - b * 222;
  const int sizes[8]  = {48, 48, 48, 48, 8, 20, 1, 1};
  const int outoff[8] = {0, 96, 192, 288, 384, 400, 440, 442};
  int h = 0, basec = 0;
  while (h < 7 && j >= basec + sizes[h]) { basec += sizes[h]; ++h; }
  int col = j - basec;
  const bf16* wp = W[h]; int nc = sizes[h];
  float s = (float)Bi[h][col];
  for (int k = 0; k < 512; k++) s += pooled[b * 512 + k] * (float)wp[k * nc + col];
  int e = outoff[h] + b * nc + col;
  if (flag[0]) ((bf16*)outv)[e] = __float2bfloat16(s);
  else         ((float*)outv)[e] = s;
}

__global__ void outstore_k(const bf16* __restrict__ nm, void* __restrict__ outv,
                           const int* __restrict__ flag)
{
  int i = blockIdx.x * 256 + threadIdx.x; if (i >= 131072) return;
  if (flag[0]) ((bf16*)outv)[444 + i] = nm[i];
  else         ((float*)outv)[444 + i] = (float)nm[i];
}

// ---------------------------------------------------------------------------

static inline void gemm(hipStream_t st, const bf16* A, int lda, long long sAb, long long sAh,
                        const bf16* B, int ldb, long long sBb, long long sBh,
                        bf16* C, int ldc, long long sCb, long long sCh,
                        int M, int N, int K, int BZ, int HZ,
                        const bf16* bias, const bf16* res, int ldres,
                        const float* extra, int extraDiv, float alpha, int mode)
{
  dim3 g((N + 63) / 64, (M + 63) / 64, BZ * HZ);
  gemm_k<<<g, dim3(256), 0, st>>>(A, lda, sAb, sAh, B, ldb, sBb, sBh, C, ldc, sCb, sCh,
                                  M, N, K, HZ, bias, res, ldres, extra, extraDiv, alpha, mode);
}

static inline void transp(hipStream_t st, const bf16* in, bf16* out, int R, int C, int Rpad,
                          long long inB, long long outB, int Z)
{
  dim3 g((C + 31) / 32, (Rpad + 31) / 32, Z);
  transpose_k<<<g, dim3(256), 0, st>>>(in, out, R, C, Rpad, inB, outB);
}

extern "C" void kernel_launch(void* const* d_in, const int* in_sizes, int n_in,
                              void* d_out, int out_size, void* d_ws, size_t ws_size,
                              hipStream_t stream)
{
  (void)in_sizes; (void)n_in; (void)out_size;
  const int* fog = (const int*)d_in[3];

  static const int kSz[55] = {
    691200, 14, 131072, 76800, 512, 3584, 512,
    262144, 512, 262144, 512, 262144, 512, 262144, 512,
    524288, 512, 512, 512, 512, 512,
    1048576, 2048, 1048576, 2048, 1048576, 2048, 1048576, 2048,
    2048, 2048, 2048, 2048,
    4194304, 8192, 4194304, 2048,
    512, 1,
    24576, 48, 24576, 48, 24576, 48, 24576, 48,
    4096, 8, 10240, 20, 512, 1, 512, 1};
  static const int kIdx[55] = {
    0, 1, 2, 4, 5, 6, 7,
    8, 9, 10, 11, 12, 13, 14, 15,
    16, 17, 18, 19, 20, 21,
    22, 23, 24, 25, 26, 27, 28, 29,
    30, 31, 32, 33,
    34, 35, 36, 37,
    38, 39,
    40, 41, 42, 43, 44, 45, 46, 47,
    48, 49, 50, 51, 52, 53, 54, 55};

  CvtArgs ca;
  size_t cum[55]; int coffi = 0;
  for (int t = 0; t < 55; t++) {
    cum[t] = (size_t)coffi;
    ca.p[t] = d_in[kIdx[t]];
    ca.off[t] = coffi;
    ca.sz[t] = kSz[t];
    coffi += (kSz[t] + 7) & ~7;
  }
  ca.off[55] = coffi;
  size_t coff = (size_t)coffi;

  const int S = 2304, NROW = 4608, CATROW = 4864;
  const long long RS = (long long)S * 512;

  char* basep = (char*)d_ws; size_t off = 0;
  auto alloc = [&](size_t elems, size_t esz) -> void* {
    void* p = basep + off; off += (elems * esz + 255) & ~(size_t)255; return p;
  };

  bf16* canon = (bf16*)alloc(coff, 2);
  int* dflag = (int*)alloc(64, 4);
  bf16* tHex = (bf16*)alloc(512 * 160, 2);
  bf16* aPad = (bf16*)alloc((size_t)NROW * 160, 2);
  bf16* tWq = (bf16*)alloc(512 * 512, 2);
  bf16* tWk = (bf16*)alloc(512 * 512, 2);
  bf16* tWv = (bf16*)alloc(512 * 512, 2);
  bf16* tWo = (bf16*)alloc(512 * 512, 2);
  bf16* tGate = (bf16*)alloc(512 * 1024, 2);
  bf16* tLq = (bf16*)alloc(4 * 512 * 512, 2);
  bf16* tLk = (bf16*)alloc(4 * 512 * 512, 2);
  bf16* tLv = (bf16*)alloc(4 * 512 * 512, 2);
  bf16* tLo = (bf16*)alloc(4 * 512 * 512, 2);
  bf16* tF1 = (bf16*)alloc(4ULL * 2048 * 512, 2);
  bf16* tF2 = (bf16*)alloc(4ULL * 512 * 2048, 2);
  float* globF = (float*)alloc(1024, 4);
  bf16* catX = (bf16*)alloc((size_t)CATROW * 512, 2);
  bf16* Qc = (bf16*)alloc((size_t)CATROW * 512, 2);
  bf16* Kc = (bf16*)alloc((size_t)CATROW * 512, 2);
  bf16* Vc = (bf16*)alloc((size_t)CATROW * 512, 2);
  bf16* VmemT = (bf16*)alloc(16ULL * 64 * 128, 2);
  bf16* VsT = (bf16*)alloc(16ULL * 64 * S, 2);
  bf16* mo = (bf16*)alloc((size_t)NROW * 512, 2);
  bf16* tmp1 = (bf16*)alloc((size_t)NROW * 512, 2);
  bf16* xbuf = (bf16*)alloc((size_t)NROW * 512, 2);
  bf16* x2buf = (bf16*)alloc((size_t)NROW * 512, 2);
  bf16* mu0 = (bf16*)alloc(256 * 512, 2);
  bf16* mup = (bf16*)alloc(256 * 512, 2);
  bf16* catg = (bf16*)alloc(256 * 1024, 2);
  bf16* gateb = (bf16*)alloc(256 * 512, 2);
  bf16* nmpre = (bf16*)alloc(256 * 512, 2);
  bf16* nmout = (bf16*)alloc(256 * 512, 2);
  float* plog = (float*)alloc(NROW, 4);
  float* pwv = (float*)alloc(NROW, 4);
  float* pooledF = (float*)alloc(1024, 4);
  float* oAcc = (float*)alloc((size_t)NROW * 512, 4);
  float* lAcc = (float*)alloc(16 * 2304, 4);
  bf16* hbuf = (bf16*)alloc((size_t)NROW * 2048, 2);
  if (off > ws_size) return;

  detect_k<<<1, 512, 0, stream>>>((const unsigned int*)d_in[0], dflag);
  cvtall8_k<<<(coffi / 8 + 255) / 256, 256, 0, stream>>>(ca, canon, dflag);

  auto T = [&](int t) -> const bf16* { return canon + cum[t]; };
  const bf16* map_rep = T(0);
  const bf16* gfeat   = T(1);
  const bf16* memin   = T(2);
  const bf16* hex_w = T(3);  const bf16* hex_b = T(4);
  const bf16* glob_w = T(5); const bf16* glob_b = T(6);
  const bf16* mem_wq = T(7);  const bf16* mem_bq = T(8);
  const bf16* mem_wk = T(9);  const bf16* mem_bk = T(10);
  const bf16* mem_wv = T(11); const bf16* mem_bv = T(12);
  const bf16* mem_wo = T(13); const bf16* mem_bo = T(14);
  const bf16* gate_w = T(15); const bf16* gate_b = T(16);
  const bf16* mn1_g = T(17); const bf16* mn1_b = T(18);
  const bf16* mn2_g = T(19); const bf16* mn2_b = T(20);
  const bf16* lw_q = T(21); const bf16* lb_q = T(22);
  const bf16* lw_k = T(23); const bf16* lb_k = T(24);
  const bf16* lw_v = T(25); const bf16* lb_v = T(26);
  const bf16* lw_o = T(27); const bf16* lb_o = T(28);
  const bf16* ln1_g = T(29); const bf16* ln1_b = T(30);
  const bf16* ln2_g = T(31); const bf16* ln2_b = T(32);
  const bf16* ff1_w = T(33); const bf16* ff1_b = T(34);
  const bf16* ff2_w = T(35); const bf16* ff2_b = T(36);
  const bf16* pool_w = T(37); const bf16* pool_b = T(38);

  // ---- weight transposes ----
  transp(stream, hex_w, tHex, 150, 512, 160, 0, 0, 1);
  transp(stream, mem_wq, tWq, 512, 512, 512, 0, 0, 1);
  transp(stream, mem_wk, tWk, 512, 512, 512, 0, 0, 1);
  transp(stream, mem_wv, tWv, 512, 512, 512, 0, 0, 1);
  transp(stream, mem_wo, tWo, 512, 512, 512, 0, 0, 1);
  transp(stream, gate_w, tGate, 1024, 512, 1024, 0, 0, 1);
  transp(stream, lw_q, tLq, 512, 512, 512, 262144, 262144, 4);
  transp(stream, lw_k, tLk, 512, 512, 512, 262144, 262144, 4);
  transp(stream, lw_v, tLv, 512, 512, 512, 262144, 262144, 4);
  transp(stream, lw_o, tLo, 512, 512, 512, 262144, 262144, 4);
  transp(stream, ff1_w, tF1, 512, 2048, 512, 1048576, 1048576, 4);
  transp(stream, ff2_w, tF2, 2048, 512, 2048, 1048576, 1048576, 4);

  // ---- seq = map@hex_w + hex_b + glob ----
  glob_k<<<4, 256, 0, stream>>>(gfeat, glob_w, glob_b, globF);
  padA_k<<<(NROW * 160 + 255) / 256, 256, 0, stream>>>(map_rep, aPad);
  gemm(stream, aPad, 160, 0, 0, tHex, 160, 0, 0, catX, 512, 0, 0,
       NROW, 512, 160, 1, 1, hex_b, nullptr, 0, globF, S, 1.f, 1);
  hipMemcpyAsync(catX + (size_t)NROW * 512, memin, 256 * 512 * 2, hipMemcpyDeviceToDevice, stream);

  // ---- shared-weight Q/K/V over [seq ; memory] ----
  gemm(stream, catX, 512, 0, 0, tWq, 512, 0, 0, Qc, 512, 0, 0, CATROW, 512, 512, 1, 1, mem_bq, nullptr, 0, nullptr, 1, 1.f, 0);
  gemm(stream, catX, 512, 0, 0, tWk, 512, 0, 0, Kc, 512, 0, 0, CATROW, 512, 512, 1, 1, mem_bk, nullptr, 0, nullptr, 1, 1.f, 0);
  gemm(stream, catX, 512, 0, 0, tWv, 512, 0, 0, Vc, 512, 0, 0, CATROW, 512, 512, 1, 1, mem_bv, nullptr, 0, nullptr, 1, 1.f, 0);

  // ---- mem_out = MHA(seq, memory, memory), flash ----
  headT_k<<<dim3(4, 2, 16), 256, 0, stream>>>(Vc, VmemT, 128, NROW, 128);
  hipMemsetAsync(oAcc, 0, (size_t)NROW * 512 * 4, stream);
  hipMemsetAsync(lAcc, 0, 16 * 2304 * 4, stream);
  flash_k<<<dim3(36, 16, 1), 256, 0, stream>>>(Qc, RS, Kc + (size_t)NROW * 512, 128 * 512,
                                               VmemT, 64 * 128, oAcc, RS, lAcc, 2304,
                                               nullptr, 2, 128);
  fdiv4_k<<<(NROW * 128 + 255) / 256, 256, 0, stream>>>(oAcc, lAcc, 2304, 2304, NROW, mo);
  gemm(stream, mo, 512, 0, 0, tWo, 512, 0, 0, tmp1, 512, 0, 0,
       NROW, 512, 512, 1, 1, mem_bo, catX, 512, nullptr, 1, 1.f, 4);
  ln_k<<<NROW / 4, 256, 0, stream>>>(tmp1, mn1_g, mn1_b, xbuf);

  // ---- mem_upd = MHA(memory, seq, seq), flash split-K + gated update ----
  headT_k<<<dim3(72, 2, 16), 256, 0, stream>>>(Vc, VsT, S, 0, S);
  hipMemsetAsync(oAcc, 0, 256 * 512 * 4, stream);
  hipMemsetAsync(lAcc, 0, 16 * 128 * 4, stream);
  flash_k<<<dim3(2, 16, 6), 256, 0, stream>>>(Qc + (size_t)NROW * 512, 128 * 512, Kc, RS,
                                              VsT, 64LL * S, oAcc, 128 * 512, lAcc, 128,
                                              nullptr, 6, S);
  fdiv4_k<<<(256 * 128 + 255) / 256, 256, 0, stream>>>(oAcc, lAcc, 128, 128, 256, mu0);
  gemm(stream, mu0, 512, 0, 0, tWo, 512, 0, 0, mup, 512, 0, 0,
       256, 512, 512, 1, 1, mem_bo, nullptr, 0, nullptr, 1, 1.f, 0);
  catg_k<<<(256 * 1024 + 255) / 256, 256, 0, stream>>>(memin, mup, catg);
  gemm(stream, catg, 1024, 0, 0, tGate, 1024, 0, 0, gateb, 512, 0, 0,
       256, 512, 1024, 1, 1, gate_b, nullptr, 0, nullptr, 1, 1.f, 5);
  gcomb_k<<<(131072 + 255) / 256, 256, 0, stream>>>(gateb, mup, memin, nmpre);
  ln_k<<<64, 256, 0, stream>>>(nmpre, mn2_g, mn2_b, nmout);
  outstore_k<<<(131072 + 255) / 256, 256, 0, stream>>>(nmout, d_out, dflag);

  // ---- transformer layers ----
  for (int l = 0; l < 4; l++) {
    gemm(stream, xbuf, 512, 0, 0, tLq + (size_t)l * 262144, 512, 0, 0, Qc, 512, 0, 0,
         NROW, 512, 512, 1, 1, lb_q + l * 512, nullptr, 0, nullptr, 1, 1.f, 0);
    gemm(stream, xbuf, 512, 0, 0, tLk + (size_t)l * 262144, 512, 0, 0, Kc, 512, 0, 0,
         NROW, 512, 512, 1, 1, lb_k + l * 512, nullptr, 0, nullptr, 1, 1.f, 0);
    gemm(stream, xbuf, 512, 0, 0, tLv + (size_t)l * 262144, 512, 0, 0, Vc, 512, 0, 0,
         NROW, 512, 512, 1, 1, lb_v + l * 512, nullptr, 0, nullptr, 1, 1.f, 0);
    headT_k<<<dim3(72, 2, 16), 256, 0, stream>>>(Vc, VsT, S, 0, S);
    hipMemsetAsync(oAcc, 0, (size_t)NROW * 512 * 4, stream);
    hipMemsetAsync(lAcc, 0, 16 * 2304 * 4, stream);
    flash_k<<<dim3(36, 16, 2), 256, 0, stream>>>(Qc, RS, Kc, RS, VsT, 64LL * S,
                                                 oAcc, RS, lAcc, 2304, fog, 18, S);
    fdiv4_k<<<(NROW * 128 + 255) / 256, 256, 0, stream>>>(oAcc, lAcc, 2304, 2304, NROW, mo);
    gemm(stream, mo, 512, 0, 0, tLo + (size_t)l * 262144, 512, 0, 0, tmp1, 512, 0, 0,
         NROW, 512, 512, 1, 1, lb_o + l * 512, xbuf, 512, nullptr, 1, 1.f, 4);
    ln_k<<<NROW / 4, 256, 0, stream>>>(tmp1, ln1_g + l * 512, ln1_b + l * 512, x2buf);
    gemm(stream, x2buf, 512, 0, 0, tF1 + (size_t)l * 1048576, 512, 0, 0, hbuf, 2048, 0, 0,
         NROW, 2048, 512, 1, 1, ff1_b + l * 2048, nullptr, 0, nullptr, 1, 1.f, 2);
    gemm(stream, hbuf, 2048, 0, 0, tF2 + (size_t)l * 1048576, 2048, 0, 0, tmp1, 512, 0, 0,
         NROW, 512, 2048, 1, 1, ff2_b + l * 512, x2buf, 512, nullptr, 1, 1.f, 4);
    ln_k<<<NROW / 4, 256, 0, stream>>>(tmp1, ln2_g + l * 512, ln2_b + l * 512, xbuf);
  }

  // ---- attention pooling + heads ----
  plog_k<<<NROW, 64, 0, stream>>>(xbuf, pool_w, pool_b, plog);
  psm_k<<<2, 256, 0, stream>>>(plog, pwv);
  hipMemsetAsync(pooledF, 0, 1024 * sizeof(float), stream);
  pool1_k<<<dim3(36, 2), 256, 0, stream>>>(pwv, xbuf, pooledF);

  heads_k<<<2, 256, 0, stream>>>(pooledF,
      T(39), T(40), T(41), T(42), T(43), T(44), T(45), T(46),
      T(47), T(48), T(49), T(50), T(51), T(52), T(53), T(54),
      d_out, dflag);
}

// Round 10
// 1087.484 us; speedup vs baseline: 1.1709x; 1.0890x over previous
//
#include <hip/hip_runtime.h>
#include <hip/hip_bf16.h>

typedef __hip_bfloat16 bf16;
typedef unsigned short u16;
typedef __attribute__((ext_vector_type(8))) short short8;
typedef __attribute__((ext_vector_type(4))) float f32x4;

__device__ inline float b2f(u16 u){ unsigned int x = ((unsigned int)u) << 16; float f; __builtin_memcpy(&f, &x, 4); return f; }
__device__ inline u16 f2bits(float f){ __hip_bfloat16 h = __float2bfloat16(f); u16 u; __builtin_memcpy(&u, &h, 2); return u; }
__device__ inline void unpk(unsigned int w, float& a, float& b){ a = b2f((u16)(w & 0xffffu)); b = b2f((u16)(w >> 16)); }

// pack two fp32 -> bf16x2 (round via +0x8000, then byte-perm) [verified r7]
__device__ __forceinline__ unsigned int pkbf(float a, float b)
{
  unsigned int ua = __float_as_uint(a) + 0x8000u;
  unsigned int ub = __float_as_uint(b) + 0x8000u;
  return __builtin_amdgcn_perm(ub, ua, 0x07060302u);
}

// ---------------------------------------------------------------------------
// dtype detection (verified round 2)
// ---------------------------------------------------------------------------
__global__ __launch_bounds__(512) void detect_k(const unsigned int* __restrict__ raw, int* __restrict__ flag)
{
  __shared__ int cnt;
  if (threadIdx.x == 0) cnt = 0;
  __syncthreads();
  unsigned int w = raw[threadIdx.x];
  unsigned int b = w & 0x7fffu;
  int pat = (b >= 0x2000u && b <= 0x4400u) ? 1 : 0;
#pragma unroll
  for (int o = 32; o; o >>= 1) pat += __shfl_xor(pat, o);
  if ((threadIdx.x & 63) == 0) atomicAdd(&cnt, pat);
  __syncthreads();
  if (threadIdx.x == 0) flag[0] = (cnt > 320) ? 1 : 0;
}

struct CvtArgs { const void* p[55]; int off[56]; int sz[55]; };

// vectorized x8 conversion (verified round 5)
__global__ __launch_bounds__(256) void cvtall8_k(CvtArgs a, bf16* __restrict__ dst,
                                                 const int* __restrict__ flag)
{
  int g8 = blockIdx.x * 256 + threadIdx.x;
  int gid = g8 * 8;
  if (gid >= a.off[55]) return;
  int lo = 0, hi = 54;
  while (lo < hi) { int mid = (lo + hi + 1) >> 1; if (gid >= a.off[mid]) lo = mid; else hi = mid - 1; }
  int t = lo, i = gid - a.off[t];
  int n = a.sz[t];
  uint4 ov;
  if (flag[0]) {
    const u16* src = (const u16*)a.p[t];
    if (i + 8 <= n) {
      ov = *(const uint4*)(src + i);
    } else {
      u16 tmp[8];
#pragma unroll
      for (int j = 0; j < 8; j++) tmp[j] = (i + j < n) ? src[i + j] : (u16)0;
      __builtin_memcpy(&ov, tmp, 16);
    }
  } else {
    const float* src = (const float*)a.p[t];
    float v[8];
    if (i + 8 <= n) {
      uint4 f0 = *(const uint4*)(src + i);
      uint4 f1 = *(const uint4*)(src + i + 4);
      __builtin_memcpy(&v[0], &f0, 16);
      __builtin_memcpy(&v[4], &f1, 16);
    } else {
#pragma unroll
      for (int j = 0; j < 8; j++) v[j] = (i + j < n) ? src[i + j] : 0.f;
    }
    u16 o8[8];
#pragma unroll
    for (int j = 0; j < 8; j++) o8[j] = f2bits(v[j]);
    __builtin_memcpy(&ov, o8, 16);
  }
  *(uint4*)((u16*)dst + gid) = ov;
}

// ---------------------------------------------------------------------------
// 64-tile GEMM (verified r2) + register prefetch (verified r6)
// mode: 0 plain(+bias), 1 +bias+extra, 2 gelu(+bias), 3 scale, 4 +bias+res, 5 sigmoid
// ---------------------------------------------------------------------------
__global__ __launch_bounds__(256) void gemm_k(
    const bf16* __restrict__ A, int lda, long long sAb, long long sAh,
    const bf16* __restrict__ B, int ldb, long long sBb, long long sBh,
    bf16* __restrict__ C, int ldc, long long sCb, long long sCh,
    int M, int N, int K, int HZ,
    const bf16* __restrict__ bias,
    const bf16* __restrict__ res, int ldres,
    const float* __restrict__ extra, int extraDiv,
    float alpha, int mode)
{
  __shared__ u16 As[64][40];
  __shared__ u16 Bs[64][40];
  int z = blockIdx.z;
  int bz = z / HZ, hz = z - bz * HZ;
  A += (size_t)bz * sAb + (size_t)hz * sAh;
  B += (size_t)bz * sBb + (size_t)hz * sBh;
  C += (size_t)bz * sCb + (size_t)hz * sCh;

  int m0 = blockIdx.y * 64, n0 = blockIdx.x * 64;
  int t = threadIdx.x;
  int r = t >> 2, c0 = (t & 3) << 3;
  int lane = t & 63, wv = t >> 6, lr = lane & 15, lq = lane >> 4;

  f32x4 acc[4];
#pragma unroll
  for (int i = 0; i < 4; i++) acc[i] = (f32x4){0.f, 0.f, 0.f, 0.f};

  const u16* Ag = (const u16*)A;
  const u16* Bg = (const u16*)B;
  bool aok = (m0 + r < M), bok = (n0 + r < N);
  const u16* arow = Ag + (size_t)(m0 + r) * lda + c0;
  const u16* brow = Bg + (size_t)(n0 + r) * ldb + c0;

  uint4 av = {0u,0u,0u,0u}, bv = {0u,0u,0u,0u};
  if (aok) av = *(const uint4*)(arow);
  if (bok) bv = *(const uint4*)(brow);

  for (int kt = 0; kt < K; kt += 32) {
    __syncthreads();
    *(uint4*)&As[r][c0] = av;
    *(uint4*)&Bs[r][c0] = bv;
    uint4 av2 = {0u,0u,0u,0u}, bv2 = {0u,0u,0u,0u};
    int nk = kt + 32;
    if (nk < K) {
      if (aok) av2 = *(const uint4*)(arow + nk);
      if (bok) bv2 = *(const uint4*)(brow + nk);
    }
    __syncthreads();
    short8 af = *(const short8*)&As[wv * 16 + lr][lq * 8];
#pragma unroll
    for (int nt = 0; nt < 4; nt++) {
      short8 bfr = *(const short8*)&Bs[nt * 16 + lr][lq * 8];
      acc[nt] = __builtin_amdgcn_mfma_f32_16x16x32_bf16(af, bfr, acc[nt], 0, 0, 0);
    }
    av = av2; bv = bv2;
  }

#pragma unroll
  for (int nt = 0; nt < 4; nt++) {
    int nn = n0 + nt * 16 + lr;
    if (nn >= N) continue;
    float bb = bias ? (float)bias[nn] : 0.f;
#pragma unroll
    for (int rr = 0; rr < 4; rr++) {
      int mm = m0 + wv * 16 + lq * 4 + rr;
      if (mm >= M) continue;
      float v = acc[nt][rr] * alpha + bb;
      if (mode == 1)      v += extra[(mm / extraDiv) * 512 + nn];
      else if (mode == 2) v = 0.5f * v * (1.f + erff(v * 0.70710678118654752f));
      else if (mode == 4) v += (float)res[(size_t)mm * ldres + nn];
      else if (mode == 5) v = 1.f / (1.f + expf(-v));
      C[(size_t)mm * ldc + nn] = __float2bfloat16(v);
    }
  }
}

// ---------------------------------------------------------------------------
// Flash v6: fixed-max split-K + XOR-swizzle (r7) + mask-AND + ones-MFMA l (r8)
// + reg-prefetched staging (r9) + raw v_exp_f32 + Q/K row-stride params
// (fused-QKV layout).
// ---------------------------------------------------------------------------
__device__ __forceinline__ int swz(int row, int cg)
{
  return row * 64 + ((cg ^ (row & 3) ^ (((row >> 3) & 1) << 2)) << 3);
}

__global__ __launch_bounds__(256) void flash_k(
    const bf16* __restrict__ Qp, long long sQb, int sQr,
    const bf16* __restrict__ Kp, long long sKb, int sKr,
    const bf16* __restrict__ VTp, long long sVz,
    float* __restrict__ oAcc, long long sOb,
    float* __restrict__ lAcc, int Ml,
    const int* __restrict__ fog,
    int tilesPerSplit, int SkLen)
{
  __shared__ u16 Kl[64 * 64];
  __shared__ u16 Vl[64 * 64];
  __shared__ u16 fgl16[2304];

  const float SC = 0.125f * 1.44269504088896340736f;
  int z = blockIdx.y, b = z >> 3, h = z & 7;
  int qt = blockIdx.x;
  int kt0 = blockIdx.z * tilesPerSplit;
  int t = threadIdx.x, lane = t & 63, w = t >> 6;
  int lr = lane & 15, lq = lane >> 4;
  int useMask = (fog != nullptr);

  const u16* Qg = (const u16*)Qp + (size_t)b * sQb + h * 64;
  const u16* Kg = (const u16*)Kp + (size_t)b * sKb + h * 64;
  const u16* Vg = (const u16*)VTp + (size_t)z * sVz;

  if (useMask) {
    for (int j = t; j < SkLen; j += 256) fgl16[j] = fog[b * 2304 + j] ? 0xFFFFu : 0u;
  }

  int qrow = qt * 64 + w * 16 + lr;
  short8 qf0, qf1;
  {
    union { short8 s; u16 u[8]; } i0, i1, o0, o1;
    i0.s = *(const short8*)(Qg + (size_t)qrow * sQr + lq * 8);
    i1.s = *(const short8*)(Qg + (size_t)qrow * sQr + 32 + lq * 8);
#pragma unroll
    for (int j = 0; j < 8; j++) {
      o0.u[j] = f2bits(b2f(i0.u[j]) * SC);
      o1.u[j] = f2bits(b2f(i1.u[j]) * SC);
    }
    qf0 = o0.s; qf1 = o1.s;
  }

  short8 ones8;
  {
    union { short8 s; u16 u[8]; } on;
#pragma unroll
    for (int j = 0; j < 8; j++) on.u[j] = 0x3F80u;
    ones8 = on.s;
  }

  int rowA[4], kAd0[4], kAd1[4];
#pragma unroll
  for (int nt = 0; nt < 4; nt++) {
    rowA[nt] = 32 * (nt >> 1) + 8 * (lr >> 2) + 4 * (nt & 1) + (lr & 3);
    kAd0[nt] = swz(rowA[nt], lq);
    kAd1[nt] = swz(rowA[nt], lq + 4);
  }
  int vAd0[4], vAd1[4];
#pragma unroll
  for (int dt = 0; dt < 4; dt++) {
    vAd0[dt] = swz(dt * 16 + lr, lq);
    vAd1[dt] = swz(dt * 16 + lr, lq + 4);
  }

  f32x4 o[4], ol;
#pragma unroll
  for (int i = 0; i < 4; i++) o[i] = (f32x4){0.f, 0.f, 0.f, 0.f};
  ol = (f32x4){0.f, 0.f, 0.f, 0.f};

  int rr = t >> 2, cg = t & 3, cs = cg * 8;
  int wAd0 = swz(rr, cg), wAd1 = swz(rr, cg + 4);

  const u16* krow = Kg + (size_t)(kt0 * 64 + rr) * sKr + cs;
  const u16* vrow = Vg + (size_t)rr * SkLen + kt0 * 64 + cs;
  uint4 ka = *(const uint4*)(krow);
  uint4 kb = *(const uint4*)(krow + 32);
  uint4 va = *(const uint4*)(vrow);
  uint4 vb = *(const uint4*)(vrow + 32);

  for (int kti = 0; kti < tilesPerSplit; kti++) {
    int kt = kt0 + kti;
    __syncthreads();
    *(uint4*)&Kl[wAd0] = ka;
    *(uint4*)&Kl[wAd1] = kb;
    *(uint4*)&Vl[wAd0] = va;
    *(uint4*)&Vl[wAd1] = vb;
    if (kti + 1 < tilesPerSplit) {
      krow += (size_t)64 * sKr;
      vrow += 64;
      ka = *(const uint4*)(krow);
      kb = *(const uint4*)(krow + 32);
      va = *(const uint4*)(vrow);
      vb = *(const uint4*)(vrow + 32);
    }
    __syncthreads();

    f32x4 s[4];
#pragma unroll
    for (int nt = 0; nt < 4; nt++) {
      s[nt] = (f32x4){0.f, 0.f, 0.f, 0.f};
      short8 kf0 = *(const short8*)&Kl[kAd0[nt]];
      short8 kf1 = *(const short8*)&Kl[kAd1[nt]];
      s[nt] = __builtin_amdgcn_mfma_f32_16x16x32_bf16(kf0, qf0, s[nt], 0, 0, 0);
      s[nt] = __builtin_amdgcn_mfma_f32_16x16x32_bf16(kf1, qf1, s[nt], 0, 0, 0);
    }

    union { unsigned int u[4]; short8 s8; } pk0, pk1;
#pragma unroll
    for (int nt = 0; nt < 4; nt++) {
      float p0 = __builtin_amdgcn_exp2f(s[nt][0]);
      float p1 = __builtin_amdgcn_exp2f(s[nt][1]);
      float p2 = __builtin_amdgcn_exp2f(s[nt][2]);
      float p3 = __builtin_amdgcn_exp2f(s[nt][3]);
      unsigned int w0 = pkbf(p0, p1);
      unsigned int w1 = pkbf(p2, p3);
      if (useMask) {
        int key = kt * 64 + 32 * (nt >> 1) + 8 * lq + 4 * (nt & 1);
        uint2 mm = *(const uint2*)&fgl16[key];
        w0 &= mm.x; w1 &= mm.y;
      }
      if (nt < 2) { pk0.u[(nt & 1) * 2] = w0; pk0.u[(nt & 1) * 2 + 1] = w1; }
      else        { pk1.u[(nt & 1) * 2] = w0; pk1.u[(nt & 1) * 2 + 1] = w1; }
    }
#pragma unroll
    for (int dt = 0; dt < 4; dt++) {
      short8 vf0 = *(const short8*)&Vl[vAd0[dt]];
      short8 vf1 = *(const short8*)&Vl[vAd1[dt]];
      o[dt] = __builtin_amdgcn_mfma_f32_16x16x32_bf16(pk0.s8, vf0, o[dt], 0, 0, 0);
      o[dt] = __builtin_amdgcn_mfma_f32_16x16x32_bf16(pk1.s8, vf1, o[dt], 0, 0, 0);
    }
    ol = __builtin_amdgcn_mfma_f32_16x16x32_bf16(pk0.s8, ones8, ol, 0, 0, 0);
    ol = __builtin_amdgcn_mfma_f32_16x16x32_bf16(pk1.s8, ones8, ol, 0, 0, 0);
  }

  if (lr == 0) {
#pragma unroll
    for (int r2 = 0; r2 < 4; r2++)
      atomicAdd(&lAcc[z * Ml + qt * 64 + w * 16 + lq * 4 + r2], ol[r2]);
  }

  float* ob = oAcc + (size_t)b * sOb;
  int qb = qt * 64 + w * 16 + lq * 4;
#pragma unroll
  for (int dt = 0; dt < 4; dt++)
#pragma unroll
    for (int r2 = 0; r2 < 4; r2++)
      atomicAdd(&ob[(size_t)(qb + r2) * 512 + h * 64 + dt * 16 + lr], o[dt][r2]);
}

// normalize, vectorized x4
__global__ __launch_bounds__(256) void fdiv4_k(const float* __restrict__ oAcc,
                                               const float* __restrict__ lAcc,
                                               int Mq, int Ml, int rows,
                                               bf16* __restrict__ out)
{
  int i = (blockIdx.x * 256 + threadIdx.x) * 4;
  if (i >= rows * 512) return;
  int row = i >> 9, col = i & 511;
  int b = row / Mq, q = row - b * Mq;
  int zz = b * 8 + (col >> 6);
  float l = lAcc[zz * Ml + q];
  float inv = (l > 0.f) ? 1.f / l : 0.f;
  float4 v = *(const float4*)(oAcc + i);
  u16 o4[4] = {f2bits(v.x * inv), f2bits(v.y * inv), f2bits(v.z * inv), f2bits(v.w * inv)};
  unsigned int lo = o4[0] | ((unsigned)o4[1] << 16);
  unsigned int hi = o4[2] | ((unsigned)o4[3] << 16);
  *(uint2*)((u16*)out + i) = (uint2){lo, hi};
}

// zero two fp32 buffers in one dispatch
__global__ __launch_bounds__(256) void zero2_k(float* __restrict__ p1, int n1,
                                               float* __restrict__ p2, int n2)
{
  int i = blockIdx.x * 256 + threadIdx.x;
  if (i < n1) p1[i] = 0.f;
  if (i < n2) p2[i] = 0.f;
}

// fused bias assembly: out[5][1536] = {mem, layer0..3} x {q|k|v}
__global__ void biasfuse_k(const bf16* __restrict__ mbq, const bf16* __restrict__ mbk,
                           const bf16* __restrict__ mbv, const bf16* __restrict__ lbq,
                           const bf16* __restrict__ lbk, const bf16* __restrict__ lbv,
                           bf16* __restrict__ out)
{
  int j = blockIdx.x * 256 + threadIdx.x;
  if (j >= 5 * 1536) return;
  int g = j / 1536, r = j - g * 1536;
  int which = r >> 9, c = r & 511;
  const bf16* src;
  if (g == 0) src = (which == 0) ? mbq : (which == 1) ? mbk : mbv;
  else {
    const bf16* base = (which == 0) ? lbq : (which == 1) ? lbk : lbv;
    src = base + (g - 1) * 512;
  }
  out[j] = src[c];
}

// in [R,C] row-major -> out [C,Rpad], zero-filled for src rows >= R
__global__ __launch_bounds__(256) void transpose_k(const bf16* __restrict__ in, bf16* __restrict__ out,
                                                   int R, int C, int Rpad, long long inB, long long outB)
{
  __shared__ u16 tile[32][33];
  const u16* ip = (const u16*)in + (size_t)blockIdx.z * inB;
  u16* op = (u16*)out + (size_t)blockIdx.z * outB;
  int c0 = blockIdx.x * 32, r0 = blockIdx.y * 32;
  int tx = threadIdx.x & 31, ty = threadIdx.x >> 5;
#pragma unroll
  for (int j = 0; j < 4; j++) {
    int rr = r0 + ty + j * 8, cc = c0 + tx;
    u16 v = 0;
    if (rr < R && cc < C) v = ip[(size_t)rr * C + cc];
    tile[ty + j * 8][tx] = v;
  }
  __syncthreads();
#pragma unroll
  for (int j = 0; j < 4; j++) {
    int oc = c0 + ty + j * 8;
    if (oc < C && r0 + tx < Rpad) op[(size_t)oc * Rpad + r0 + tx] = tile[tx][ty + j * 8];
  }
}

// head-slice transpose with input row stride
__global__ __launch_bounds__(256) void headT_k(const bf16* __restrict__ in, bf16* __restrict__ out,
                                               int Sk, int rowbase, int bstride, int instride)
{
  __shared__ u16 tile[32][33];
  int z = blockIdx.z, b = z >> 3, h = z & 7;
  const u16* ip = (const u16*)in + ((size_t)(rowbase + b * bstride)) * instride + h * 64;
  u16* op = (u16*)out + (size_t)z * 64 * Sk;
  int r0 = blockIdx.x * 32, c0 = blockIdx.y * 32;
  int tx = threadIdx.x & 31, ty = threadIdx.x >> 5;
#pragma unroll
  for (int j = 0; j < 4; j++)
    tile[ty + j * 8][tx] = ip[(size_t)(r0 + ty + j * 8) * instride + c0 + tx];
  __syncthreads();
#pragma unroll
  for (int j = 0; j < 4; j++)
    op[(size_t)(c0 + ty + j * 8) * Sk + r0 + tx] = tile[tx][ty + j * 8];
}

// row LayerNorm over D=512, 4 rows/block (wave per row)
__global__ __launch_bounds__(256) void ln_k(const bf16* __restrict__ in, const bf16* __restrict__ g,
                                            const bf16* __restrict__ bb, bf16* __restrict__ out)
{
  size_t row = blockIdx.x * 4 + (threadIdx.x >> 6);
  int lane = threadIdx.x & 63;
  const u16* ip = (const u16*)in + row * 512 + lane * 8;
  uint4 rv = *(const uint4*)ip;
  float v[8];
  unpk(rv.x, v[0], v[1]); unpk(rv.y, v[2], v[3]); unpk(rv.z, v[4], v[5]); unpk(rv.w, v[6], v[7]);
  float s = 0.f, s2 = 0.f;
#pragma unroll
  for (int k = 0; k < 8; k++) { s += v[k]; s2 += v[k] * v[k]; }
#pragma unroll
  for (int o = 32; o; o >>= 1) { s += __shfl_xor(s, o); s2 += __shfl_xor(s2, o); }
  float mean = s * (1.f / 512.f);
  float var = s2 * (1.f / 512.f) - mean * mean;
  float rstd = rsqrtf(var + 1e-5f);
  uint4 gv = *(const uint4*)((const u16*)g + lane * 8);
  uint4 bv = *(const uint4*)((const u16*)bb + lane * 8);
  float gf[8], bf2[8];
  unpk(gv.x, gf[0], gf[1]); unpk(gv.y, gf[2], gf[3]); unpk(gv.z, gf[4], gf[5]); unpk(gv.w, gf[6], gf[7]);
  unpk(bv.x, bf2[0], bf2[1]); unpk(bv.y, bf2[2], bf2[3]); unpk(bv.z, bf2[4], bf2[5]); unpk(bv.w, bf2[6], bf2[7]);
  u16 o8[8];
#pragma unroll
  for (int k = 0; k < 8; k++) o8[k] = f2bits((v[k] - mean) * rstd * gf[k] + bf2[k]);
  uint4 ov;
  ov.x = o8[0] | ((unsigned)o8[1] << 16); ov.y = o8[2] | ((unsigned)o8[3] << 16);
  ov.z = o8[4] | ((unsigned)o8[5] << 16); ov.w = o8[6] | ((unsigned)o8[7] << 16);
  *(uint4*)((u16*)out + row * 512 + lane * 8) = ov;
}

__global__ void glob_k(const bf16* __restrict__ gf, const bf16* __restrict__ gw,
                       const bf16* __restrict__ gb, float* __restrict__ out)
{
  int i = blockIdx.x * 256 + threadIdx.x; if (i >= 1024) return;
  int b = i >> 9, d = i & 511;
  float s = (float)gb[d];
#pragma unroll
  for (int f = 0; f < 7; f++) s += (float)gf[b * 7 + f] * (float)gw[f * 512 + d];
  out[i] = s;
}

__global__ void padA_k(const bf16* __restrict__ in, bf16* __restrict__ out)
{
  int i = blockIdx.x * 256 + threadIdx.x; if (i >= 4608 * 160) return;
  int r = i / 160, c = i - r * 160;
  out[i] = (c < 150) ? in[r * 150 + c] : __float2bfloat16(0.f);
}

__global__ void catg_k(const bf16* __restrict__ mem, const bf16* __restrict__ mu, bf16* __restrict__ out)
{
  int i = blockIdx.x * 256 + threadIdx.x; if (i >= 256 * 1024) return;
  int r = i >> 10, c = i & 1023;
  out[i] = (c < 512) ? mem[r * 512 + c] : mu[r * 512 + c - 512];
}

__global__ void gcomb_k(const bf16* __restrict__ g, const bf16* __restrict__ mu,
                        const bf16* __restrict__ mem, bf16* __restrict__ out)
{
  int i = blockIdx.x * 256 + threadIdx.x; if (i >= 131072) return;
  float gg = (float)g[i];
  out[i] = __float2bfloat16(gg * (float)mu[i] + (1.f - gg) * (float)mem[i]);
}

__global__ __launch_bounds__(64) void plog_k(const bf16* __restrict__ x, const bf16* __restrict__ pw,
                                             const bf16* __restrict__ pb, float* __restrict__ out)
{
  size_t row = blockIdx.x; int lane = threadIdx.x;
  uint4 xv = *(const uint4*)((const u16*)x + row * 512 + lane * 8);
  uint4 wv = *(const uint4*)((const u16*)pw + lane * 8);
  float v[8], w[8];
  unpk(xv.x, v[0], v[1]); unpk(xv.y, v[2], v[3]); unpk(xv.z, v[4], v[5]); unpk(xv.w, v[6], v[7]);
  unpk(wv.x, w[0], w[1]); unpk(wv.y, w[2], w[3]); unpk(wv.z, w[4], w[5]); unpk(wv.w, w[6], w[7]);
  float s = 0.f;
#pragma unroll
  for (int k = 0; k < 8; k++) s += v[k] * w[k];
#pragma unroll
  for (int o = 32; o; o >>= 1) s += __shfl_xor(s, o);
  if (lane == 0) out[row] = s + (float)pb[0];
}

__global__ __launch_bounds__(256) void psm_k(const float* __restrict__ lg, float* __restrict__ pw)
{
  __shared__ float red[4];
  int b = blockIdx.x, tid = threadIdx.x;
  const float* p = lg + b * 2304;
  float vals[9]; float mx = -3e38f;
#pragma unroll
  for (int i = 0; i < 9; i++) {
    int j = tid + i * 256;
    float x = (j < 2304) ? p[j] : -3e38f;
    vals[i] = x; mx = fmaxf(mx, x);
  }
#pragma unroll
  for (int o = 32; o; o >>= 1) mx = fmaxf(mx, __shfl_xor(mx, o));
  if ((tid & 63) == 0) red[tid >> 6] = mx;
  __syncthreads();
  mx = fmaxf(fmaxf(red[0], red[1]), fmaxf(red[2], red[3]));
  float sum = 0.f;
#pragma unroll
  for (int i = 0; i < 9; i++) {
    int j = tid + i * 256;
    if (j < 2304) { float e = expf(vals[i] - mx); vals[i] = e; sum += e; }
  }
  __syncthreads();
#pragma unroll
  for (int o = 32; o; o >>= 1) sum += __shfl_xor(sum, o);
  if ((tid & 63) == 0) red[tid >> 6] = sum;
  __syncthreads();
  sum = red[0] + red[1] + red[2] + red[3];
  float inv = 1.f / sum;
#pragma unroll
  for (int i = 0; i < 9; i++) {
    int j = tid + i * 256;
    if (j < 2304) pw[b * 2304 + j] = vals[i] * inv;
  }
}

__global__ __launch_bounds__(256) void pool1_k(const float* __restrict__ pw, const bf16* __restrict__ x,
                                               float* __restrict__ out)
{
  int b = blockIdx.y, chunk = blockIdx.x, t = threadIdx.x;
  float a0 = 0.f, a1 = 0.f;
  for (int s = 0; s < 64; s++) {
    int tok = chunk * 64 + s;
    float wv = pw[b * 2304 + tok];
    const u16* xp = (const u16*)x + ((size_t)(b * 2304 + tok)) * 512;
    a0 += wv * b2f(xp[t]);
    a1 += wv * b2f(xp[t + 256]);
  }
  atomicAdd(&out[b * 512 + t], a0);
  atomicAdd(&out[b * 512 + t + 256], a1);
}

__global__ void heads_k(const float* __restrict__ pooled,
                        const bf16* w0, const bf16* b0, const bf16* w1, const bf16* b1,
                        const bf16* w2, const bf16* b2, const bf16* w3, const bf16* b3,
                        const bf16* w4, const bf16* b4, const bf16* w5, const bf16* b5,
                        const bf16* w6, const bf16* b6, const bf16* w7, const bf16* b7,
                        void* __restrict__ outv, const int* __restrict__ flag)
{
  int idx = blockIdx.x * 256 + threadIdx.x; if (idx >= 444) return;
  const bf16* W[8] = {w0, w1, w2, w3, w4, w5, w6, w7};
  const bf16* Bi[8] = {b0, b1, b2, b3, b4, b5, b6, b7};
  int b = idx / 222, j = idx - b * 222;
  const int sizes[8]  = {48, 48, 48, 48, 8, 20, 1, 1};
  const int outoff[8] = {0, 96, 192, 288, 384, 400, 440, 442};
  int h = 0, basec = 0;
  while (h < 7 && j >= basec + sizes[h]) { basec += sizes[h]; ++h; }
  int col = j - basec;
  const bf16* wp = W[h]; int nc = sizes[h];
  float s = (float)Bi[h][col];
  for (int k = 0; k < 512; k++) s += pooled[b * 512 + k] * (float)wp[k * nc + col];
  int e = outoff[h] + b * nc + col;
  if (flag[0]) ((bf16*)outv)[e] = __float2bfloat16(s);
  else         ((float*)outv)[e] = s;
}

__global__ void outstore_k(const bf16* __restrict__ nm, void* __restrict__ outv,
                           const int* __restrict__ flag)
{
  int i = blockIdx.x * 256 + threadIdx.x; if (i >= 131072) return;
  if (flag[0]) ((bf16*)outv)[444 + i] = nm[i];
  else         ((float*)outv)[444 + i] = (float)nm[i];
}

// ---------------------------------------------------------------------------

static inline void gemm(hipStream_t st, const bf16* A, int lda, long long sAb, long long sAh,
                        const bf16* B, int ldb, long long sBb, long long sBh,
                        bf16* C, int ldc, long long sCb, long long sCh,
                        int M, int N, int K, int BZ, int HZ,
                        const bf16* bias, const bf16* res, int ldres,
                        const float* extra, int extraDiv, float alpha, int mode)
{
  dim3 g((N + 63) / 64, (M + 63) / 64, BZ * HZ);
  gemm_k<<<g, dim3(256), 0, st>>>(A, lda, sAb, sAh, B, ldb, sBb, sBh, C, ldc, sCb, sCh,
                                  M, N, K, HZ, bias, res, ldres, extra, extraDiv, alpha, mode);
}

static inline void transp(hipStream_t st, const bf16* in, bf16* out, int R, int C, int Rpad,
                          long long inB, long long outB, int Z)
{
  dim3 g((C + 31) / 32, (Rpad + 31) / 32, Z);
  transpose_k<<<g, dim3(256), 0, st>>>(in, out, R, C, Rpad, inB, outB);
}

extern "C" void kernel_launch(void* const* d_in, const int* in_sizes, int n_in,
                              void* d_out, int out_size, void* d_ws, size_t ws_size,
                              hipStream_t stream)
{
  (void)in_sizes; (void)n_in; (void)out_size;
  const int* fog = (const int*)d_in[3];

  static const int kSz[55] = {
    691200, 14, 131072, 76800, 512, 3584, 512,
    262144, 512, 262144, 512, 262144, 512, 262144, 512,
    524288, 512, 512, 512, 512, 512,
    1048576, 2048, 1048576, 2048, 1048576, 2048, 1048576, 2048,
    2048, 2048, 2048, 2048,
    4194304, 8192, 4194304, 2048,
    512, 1,
    24576, 48, 24576, 48, 24576, 48, 24576, 48,
    4096, 8, 10240, 20, 512, 1, 512, 1};
  static const int kIdx[55] = {
    0, 1, 2, 4, 5, 6, 7,
    8, 9, 10, 11, 12, 13, 14, 15,
    16, 17, 18, 19, 20, 21,
    22, 23, 24, 25, 26, 27, 28, 29,
    30, 31, 32, 33,
    34, 35, 36, 37,
    38, 39,
    40, 41, 42, 43, 44, 45, 46, 47,
    48, 49, 50, 51, 52, 53, 54, 55};

  CvtArgs ca;
  size_t cum[55]; int coffi = 0;
  for (int t = 0; t < 55; t++) {
    cum[t] = (size_t)coffi;
    ca.p[t] = d_in[kIdx[t]];
    ca.off[t] = coffi;
    ca.sz[t] = kSz[t];
    coffi += (kSz[t] + 7) & ~7;
  }
  ca.off[55] = coffi;
  size_t coff = (size_t)coffi;

  const int S = 2304, NROW = 4608, CATROW = 4864;
  const long long QR = 1536;                 // fused QKV row stride
  const long long RSQ = (long long)S * QR;   // per-b row block in fused [*,1536]

  char* basep = (char*)d_ws; size_t off = 0;
  auto alloc = [&](size_t elems, size_t esz) -> void* {
    void* p = basep + off; off += (elems * esz + 255) & ~(size_t)255; return p;
  };

  bf16* canon = (bf16*)alloc(coff, 2);
  int* dflag = (int*)alloc(64, 4);
  bf16* tHex = (bf16*)alloc(512 * 160, 2);
  bf16* aPad = (bf16*)alloc((size_t)NROW * 160, 2);
  bf16* tQKVmem = (bf16*)alloc(1536 * 512, 2);
  bf16* tWo = (bf16*)alloc(512 * 512, 2);
  bf16* tGate = (bf16*)alloc(512 * 1024, 2);
  bf16* tLqkv = (bf16*)alloc(4ULL * 1536 * 512, 2);
  bf16* tLo = (bf16*)alloc(4 * 512 * 512, 2);
  bf16* tF1 = (bf16*)alloc(4ULL * 2048 * 512, 2);
  bf16* tF2 = (bf16*)alloc(4ULL * 512 * 2048, 2);
  bf16* fbias = (bf16*)alloc(5 * 1536, 2);
  float* globF = (float*)alloc(1024, 4);
  bf16* catX = (bf16*)alloc((size_t)CATROW * 512, 2);
  bf16* QKV = (bf16*)alloc((size_t)CATROW * 1536, 2);
  bf16* VmemT = (bf16*)alloc(16ULL * 64 * 128, 2);
  bf16* VsT = (bf16*)alloc(16ULL * 64 * S, 2);
  bf16* mo = (bf16*)alloc((size_t)NROW * 512, 2);
  bf16* tmp1 = (bf16*)alloc((size_t)NROW * 512, 2);
  bf16* xbuf = (bf16*)alloc((size_t)NROW * 512, 2);
  bf16* x2buf = (bf16*)alloc((size_t)NROW * 512, 2);
  bf16* mu0 = (bf16*)alloc(256 * 512, 2);
  bf16* mup = (bf16*)alloc(256 * 512, 2);
  bf16* catg = (bf16*)alloc(256 * 1024, 2);
  bf16* gateb = (bf16*)alloc(256 * 512, 2);
  bf16* nmpre = (bf16*)alloc(256 * 512, 2);
  bf16* nmout = (bf16*)alloc(256 * 512, 2);
  float* plog = (float*)alloc(NROW, 4);
  float* pwv = (float*)alloc(NROW, 4);
  float* pooledF = (float*)alloc(1024, 4);
  float* oAcc = (float*)alloc((size_t)NROW * 512, 4);
  float* lAcc = (float*)alloc(16 * 2304, 4);
  bf16* hbuf = (bf16*)alloc((size_t)NROW * 2048, 2);
  if (off > ws_size) return;

  detect_k<<<1, 512, 0, stream>>>((const unsigned int*)d_in[0], dflag);
  cvtall8_k<<<(coffi / 8 + 255) / 256, 256, 0, stream>>>(ca, canon, dflag);

  auto T = [&](int t) -> const bf16* { return canon + cum[t]; };
  const bf16* map_rep = T(0);
  const bf16* gfeat   = T(1);
  const bf16* memin   = T(2);
  const bf16* hex_w = T(3);  const bf16* hex_b = T(4);
  const bf16* glob_w = T(5); const bf16* glob_b = T(6);
  const bf16* mem_wq = T(7);  const bf16* mem_bq = T(8);
  const bf16* mem_wk = T(9);  const bf16* mem_bk = T(10);
  const bf16* mem_wv = T(11); const bf16* mem_bv = T(12);
  const bf16* mem_wo = T(13); const bf16* mem_bo = T(14);
  const bf16* gate_w = T(15); const bf16* gate_b = T(16);
  const bf16* mn1_g = T(17); const bf16* mn1_b = T(18);
  const bf16* mn2_g = T(19); const bf16* mn2_b = T(20);
  const bf16* lw_q = T(21); const bf16* lb_q = T(22);
  const bf16* lw_k = T(23); const bf16* lb_k = T(24);
  const bf16* lw_v = T(25); const bf16* lb_v = T(26);
  const bf16* lw_o = T(27); const bf16* lb_o = T(28);
  const bf16* ln1_g = T(29); const bf16* ln1_b = T(30);
  const bf16* ln2_g = T(31); const bf16* ln2_b = T(32);
  const bf16* ff1_w = T(33); const bf16* ff1_b = T(34);
  const bf16* ff2_w = T(35); const bf16* ff2_b = T(36);
  const bf16* pool_w = T(37); const bf16* pool_b = T(38);

  // ---- weight transposes (fused QKV blocks) + fused biases ----
  transp(stream, hex_w, tHex, 150, 512, 160, 0, 0, 1);
  transp(stream, mem_wq, tQKVmem, 512, 512, 512, 0, 0, 1);
  transp(stream, mem_wk, tQKVmem + 262144, 512, 512, 512, 0, 0, 1);
  transp(stream, mem_wv, tQKVmem + 524288, 512, 512, 512, 0, 0, 1);
  transp(stream, mem_wo, tWo, 512, 512, 512, 0, 0, 1);
  transp(stream, gate_w, tGate, 1024, 512, 1024, 0, 0, 1);
  transp(stream, lw_q, tLqkv, 512, 512, 512, 262144, 786432, 4);
  transp(stream, lw_k, tLqkv + 262144, 512, 512, 512, 262144, 786432, 4);
  transp(stream, lw_v, tLqkv + 524288, 512, 512, 512, 262144, 786432, 4);
  transp(stream, lw_o, tLo, 512, 512, 512, 262144, 262144, 4);
  transp(stream, ff1_w, tF1, 512, 2048, 512, 1048576, 1048576, 4);
  transp(stream, ff2_w, tF2, 2048, 512, 2048, 1048576, 1048576, 4);
  biasfuse_k<<<(5 * 1536 + 255) / 256, 256, 0, stream>>>(mem_bq, mem_bk, mem_bv,
                                                         lb_q, lb_k, lb_v, fbias);

  // ---- seq = map@hex_w + hex_b + glob ----
  glob_k<<<4, 256, 0, stream>>>(gfeat, glob_w, glob_b, globF);
  padA_k<<<(NROW * 160 + 255) / 256, 256, 0, stream>>>(map_rep, aPad);
  gemm(stream, aPad, 160, 0, 0, tHex, 160, 0, 0, catX, 512, 0, 0,
       NROW, 512, 160, 1, 1, hex_b, nullptr, 0, globF, S, 1.f, 1);
  hipMemcpyAsync(catX + (size_t)NROW * 512, memin, 256 * 512 * 2, hipMemcpyDeviceToDevice, stream);

  // ---- fused shared-weight QKV over [seq ; memory] ----
  gemm(stream, catX, 512, 0, 0, tQKVmem, 512, 0, 0, QKV, 1536, 0, 0,
       CATROW, 1536, 512, 1, 1, fbias, nullptr, 0, nullptr, 1, 1.f, 0);

  // ---- mem_out = MHA(seq, memory, memory), flash ----
  headT_k<<<dim3(4, 2, 16), 256, 0, stream>>>(QKV + 1024, VmemT, 128, NROW, 128, 1536);
  zero2_k<<<(NROW * 512 + 255) / 256, 256, 0, stream>>>(oAcc, NROW * 512, lAcc, 16 * 2304);
  flash_k<<<dim3(36, 16, 1), 256, 0, stream>>>(
      QKV, RSQ, 1536, QKV + (size_t)NROW * 1536 + 512, 128 * QR, 1536,
      VmemT, 64 * 128, oAcc, (long long)S * 512, lAcc, 2304, nullptr, 2, 128);
  fdiv4_k<<<(NROW * 128 + 255) / 256, 256, 0, stream>>>(oAcc, lAcc, 2304, 2304, NROW, mo);
  gemm(stream, mo, 512, 0, 0, tWo, 512, 0, 0, tmp1, 512, 0, 0,
       NROW, 512, 512, 1, 1, mem_bo, catX, 512, nullptr, 1, 1.f, 4);
  ln_k<<<NROW / 4, 256, 0, stream>>>(tmp1, mn1_g, mn1_b, xbuf);

  // ---- mem_upd = MHA(memory, seq, seq), flash split-K + gated update ----
  headT_k<<<dim3(72, 2, 16), 256, 0, stream>>>(QKV + 1024, VsT, S, 0, S, 1536);
  zero2_k<<<(256 * 512 + 255) / 256, 256, 0, stream>>>(oAcc, 256 * 512, lAcc, 16 * 128);
  flash_k<<<dim3(2, 16, 6), 256, 0, stream>>>(
      QKV + (size_t)NROW * 1536, 128 * QR, 1536, QKV + 512, RSQ, 1536,
      VsT, 64LL * S, oAcc, 128 * 512, lAcc, 128, nullptr, 6, S);
  fdiv4_k<<<(256 * 128 + 255) / 256, 256, 0, stream>>>(oAcc, lAcc, 128, 128, 256, mu0);
  gemm(stream, mu0, 512, 0, 0, tWo, 512, 0, 0, mup, 512, 0, 0,
       256, 512, 512, 1, 1, mem_bo, nullptr, 0, nullptr, 1, 1.f, 0);
  catg_k<<<(256 * 1024 + 255) / 256, 256, 0, stream>>>(memin, mup, catg);
  gemm(stream, catg, 1024, 0, 0, tGate, 1024, 0, 0, gateb, 512, 0, 0,
       256, 512, 1024, 1, 1, gate_b, nullptr, 0, nullptr, 1, 1.f, 5);
  gcomb_k<<<(131072 + 255) / 256, 256, 0, stream>>>(gateb, mup, memin, nmpre);
  ln_k<<<64, 256, 0, stream>>>(nmpre, mn2_g, mn2_b, nmout);
  outstore_k<<<(131072 + 255) / 256, 256, 0, stream>>>(nmout, d_out, dflag);

  // ---- transformer layers ----
  for (int l = 0; l < 4; l++) {
    gemm(stream, xbuf, 512, 0, 0, tLqkv + (size_t)l * 786432, 512, 0, 0, QKV, 1536, 0, 0,
         NROW, 1536, 512, 1, 1, fbias + (1 + l) * 1536, nullptr, 0, nullptr, 1, 1.f, 0);
    headT_k<<<dim3(72, 2, 16), 256, 0, stream>>>(QKV + 1024, VsT, S, 0, S, 1536);
    zero2_k<<<(NROW * 512 + 255) / 256, 256, 0, stream>>>(oAcc, NROW * 512, lAcc, 16 * 2304);
    flash_k<<<dim3(36, 16, 3), 256, 0, stream>>>(
        QKV, RSQ, 1536, QKV + 512, RSQ, 1536,
        VsT, 64LL * S, oAcc, (long long)S * 512, lAcc, 2304, fog, 12, S);
    fdiv4_k<<<(NROW * 128 + 255) / 256, 256, 0, stream>>>(oAcc, lAcc, 2304, 2304, NROW, mo);
    gemm(stream, mo, 512, 0, 0, tLo + (size_t)l * 262144, 512, 0, 0, tmp1, 512, 0, 0,
         NROW, 512, 512, 1, 1, lb_o + l * 512, xbuf, 512, nullptr, 1, 1.f, 4);
    ln_k<<<NROW / 4, 256, 0, stream>>>(tmp1, ln1_g + l * 512, ln1_b + l * 512, x2buf);
    gemm(stream, x2buf, 512, 0, 0, tF1 + (size_t)l * 1048576, 512, 0, 0, hbuf, 2048, 0, 0,
         NROW, 2048, 512, 1, 1, ff1_b + l * 2048, nullptr, 0, nullptr, 1, 1.f, 2);
    gemm(stream, hbuf, 2048, 0, 0, tF2 + (size_t)l * 1048576, 2048, 0, 0, tmp1, 512, 0, 0,
         NROW, 512, 2048, 1, 1, ff2_b + l * 512, x2buf, 512, nullptr, 1, 1.f, 4);
    ln_k<<<NROW / 4, 256, 0, stream>>>(tmp1, ln2_g + l * 512, ln2_b + l * 512, xbuf);
  }

  // ---- attention pooling + heads ----
  plog_k<<<NROW, 64, 0, stream>>>(xbuf, pool_w, pool_b, plog);
  psm_k<<<2, 256, 0, stream>>>(plog, pwv);
  hipMemsetAsync(pooledF, 0, 1024 * sizeof(float), stream);
  pool1_k<<<dim3(36, 2), 256, 0, stream>>>(pwv, xbuf, pooledF);

  heads_k<<<2, 256, 0, stream>>>(pooledF,
      T(39), T(40), T(41), T(42), T(43), T(44), T(45), T(46),
      T(47), T(48), T(49), T(50), T(51), T(52), T(53), T(54),
      d_out, dflag);
}

// Round 11
// 1077.192 us; speedup vs baseline: 1.1821x; 1.0096x over previous
//
#include <hip/hip_runtime.h>
#include <hip/hip_bf16.h>

typedef __hip_bfloat16 bf16;
typedef unsigned short u16;
typedef __attribute__((ext_vector_type(8))) short short8;
typedef __attribute__((ext_vector_type(4))) float f32x4;

__device__ inline float b2f(u16 u){ unsigned int x = ((unsigned int)u) << 16; float f; __builtin_memcpy(&f, &x, 4); return f; }
__device__ inline u16 f2bits(float f){ __hip_bfloat16 h = __float2bfloat16(f); u16 u; __builtin_memcpy(&u, &h, 2); return u; }
__device__ inline void unpk(unsigned int w, float& a, float& b){ a = b2f((u16)(w & 0xffffu)); b = b2f((u16)(w >> 16)); }

__device__ __forceinline__ unsigned int pkbf(float a, float b)
{
  unsigned int ua = __float_as_uint(a) + 0x8000u;
  unsigned int ub = __float_as_uint(b) + 0x8000u;
  return __builtin_amdgcn_perm(ub, ua, 0x07060302u);
}

// ---------------------------------------------------------------------------
// dtype detection (verified round 2)
// ---------------------------------------------------------------------------
__global__ __launch_bounds__(512) void detect_k(const unsigned int* __restrict__ raw, int* __restrict__ flag)
{
  __shared__ int cnt;
  if (threadIdx.x == 0) cnt = 0;
  __syncthreads();
  unsigned int w = raw[threadIdx.x];
  unsigned int b = w & 0x7fffu;
  int pat = (b >= 0x2000u && b <= 0x4400u) ? 1 : 0;
#pragma unroll
  for (int o = 32; o; o >>= 1) pat += __shfl_xor(pat, o);
  if ((threadIdx.x & 63) == 0) atomicAdd(&cnt, pat);
  __syncthreads();
  if (threadIdx.x == 0) flag[0] = (cnt > 320) ? 1 : 0;
}

struct CvtArgs { const void* p[55]; int off[56]; int sz[55]; };

// vectorized x8 conversion (verified round 5)
__global__ __launch_bounds__(256) void cvtall8_k(CvtArgs a, bf16* __restrict__ dst,
                                                 const int* __restrict__ flag)
{
  int g8 = blockIdx.x * 256 + threadIdx.x;
  int gid = g8 * 8;
  if (gid >= a.off[55]) return;
  int lo = 0, hi = 54;
  while (lo < hi) { int mid = (lo + hi + 1) >> 1; if (gid >= a.off[mid]) lo = mid; else hi = mid - 1; }
  int t = lo, i = gid - a.off[t];
  int n = a.sz[t];
  uint4 ov;
  if (flag[0]) {
    const u16* src = (const u16*)a.p[t];
    if (i + 8 <= n) {
      ov = *(const uint4*)(src + i);
    } else {
      u16 tmp[8];
#pragma unroll
      for (int j = 0; j < 8; j++) tmp[j] = (i + j < n) ? src[i + j] : (u16)0;
      __builtin_memcpy(&ov, tmp, 16);
    }
  } else {
    const float* src = (const float*)a.p[t];
    float v[8];
    if (i + 8 <= n) {
      uint4 f0 = *(const uint4*)(src + i);
      uint4 f1 = *(const uint4*)(src + i + 4);
      __builtin_memcpy(&v[0], &f0, 16);
      __builtin_memcpy(&v[4], &f1, 16);
    } else {
#pragma unroll
      for (int j = 0; j < 8; j++) v[j] = (i + j < n) ? src[i + j] : 0.f;
    }
    u16 o8[8];
#pragma unroll
    for (int j = 0; j < 8; j++) o8[j] = f2bits(v[j]);
    __builtin_memcpy(&ov, o8, 16);
  }
  *(uint4*)((u16*)dst + gid) = ov;
}

__device__ __forceinline__ float epi(float v, int mm, int nn,
                                     const bf16* bias, const bf16* res, int ldres,
                                     const float* extra, int extraDiv, float alpha, int mode)
{
  float bb = bias ? (float)bias[nn] : 0.f;
  v = v * alpha + bb;
  if (mode == 1)      v += extra[(mm / extraDiv) * 512 + nn];
  else if (mode == 2) v = 0.5f * v * (1.f + erff(v * 0.70710678118654752f));
  else if (mode == 4) v += (float)res[(size_t)mm * ldres + nn];
  else if (mode == 5) v = 1.f / (1.f + expf(-v));
  return v;
}

// ---------------------------------------------------------------------------
// 64-tile GEMM (verified r2) + register prefetch (verified r6)
// ---------------------------------------------------------------------------
__global__ __launch_bounds__(256) void gemm_k(
    const bf16* __restrict__ A, int lda, long long sAb, long long sAh,
    const bf16* __restrict__ B, int ldb, long long sBb, long long sBh,
    bf16* __restrict__ C, int ldc, long long sCb, long long sCh,
    int M, int N, int K, int HZ,
    const bf16* __restrict__ bias,
    const bf16* __restrict__ res, int ldres,
    const float* __restrict__ extra, int extraDiv,
    float alpha, int mode)
{
  __shared__ u16 As[64][40];
  __shared__ u16 Bs[64][40];
  int z = blockIdx.z;
  int bz = z / HZ, hz = z - bz * HZ;
  A += (size_t)bz * sAb + (size_t)hz * sAh;
  B += (size_t)bz * sBb + (size_t)hz * sBh;
  C += (size_t)bz * sCb + (size_t)hz * sCh;

  int m0 = blockIdx.y * 64, n0 = blockIdx.x * 64;
  int t = threadIdx.x;
  int r = t >> 2, c0 = (t & 3) << 3;
  int lane = t & 63, wv = t >> 6, lr = lane & 15, lq = lane >> 4;

  f32x4 acc[4];
#pragma unroll
  for (int i = 0; i < 4; i++) acc[i] = (f32x4){0.f, 0.f, 0.f, 0.f};

  const u16* Ag = (const u16*)A;
  const u16* Bg = (const u16*)B;
  bool aok = (m0 + r < M), bok = (n0 + r < N);
  const u16* arow = Ag + (size_t)(m0 + r) * lda + c0;
  const u16* brow = Bg + (size_t)(n0 + r) * ldb + c0;

  uint4 av = {0u,0u,0u,0u}, bv = {0u,0u,0u,0u};
  if (aok) av = *(const uint4*)(arow);
  if (bok) bv = *(const uint4*)(brow);

  for (int kt = 0; kt < K; kt += 32) {
    __syncthreads();
    *(uint4*)&As[r][c0] = av;
    *(uint4*)&Bs[r][c0] = bv;
    uint4 av2 = {0u,0u,0u,0u}, bv2 = {0u,0u,0u,0u};
    int nk = kt + 32;
    if (nk < K) {
      if (aok) av2 = *(const uint4*)(arow + nk);
      if (bok) bv2 = *(const uint4*)(brow + nk);
    }
    __syncthreads();
    short8 af = *(const short8*)&As[wv * 16 + lr][lq * 8];
#pragma unroll
    for (int nt = 0; nt < 4; nt++) {
      short8 bfr = *(const short8*)&Bs[nt * 16 + lr][lq * 8];
      acc[nt] = __builtin_amdgcn_mfma_f32_16x16x32_bf16(af, bfr, acc[nt], 0, 0, 0);
    }
    av = av2; bv = bv2;
  }

#pragma unroll
  for (int nt = 0; nt < 4; nt++) {
    int nn = n0 + nt * 16 + lr;
    if (nn >= N) continue;
#pragma unroll
    for (int rr = 0; rr < 4; rr++) {
      int mm = m0 + wv * 16 + lq * 4 + rr;
      if (mm >= M) continue;
      C[(size_t)mm * ldc + nn] =
          __float2bfloat16(epi(acc[nt][rr], mm, nn, bias, res, ldres, extra, extraDiv, alpha, mode));
    }
  }
}

// ---------------------------------------------------------------------------
// 128x64 tile GEMM: wave owns 32 rows x 64 cols (2x4 MFMA frags) -> MFMA:LDS
// read ratio 8:6 vs 4:5. Requires M%128==0, N%64==0, K%32==0. Grid must stay
// large (>=~900 blocks) per the r5/r8 TLP lesson.
// ---------------------------------------------------------------------------
__global__ __launch_bounds__(256) void gemmM128_k(
    const bf16* __restrict__ A, int lda,
    const bf16* __restrict__ B, int ldb,
    bf16* __restrict__ C, int ldc, int K,
    const bf16* __restrict__ bias,
    const bf16* __restrict__ res, int ldres,
    const float* __restrict__ extra, int extraDiv,
    float alpha, int mode)
{
  __shared__ u16 As[128][40];
  __shared__ u16 Bs[64][40];
  int t = threadIdx.x;
  int m0 = blockIdx.y * 128, n0 = blockIdx.x * 64;
  int lane = t & 63, w = t >> 6, lr = lane & 15, lq = lane >> 4;
  int wm = w * 32;
  int r = t >> 2, c0 = (t & 3) << 3;

  const u16* Ag = (const u16*)A;
  const u16* Bg = (const u16*)B;
  const u16* ar0 = Ag + (size_t)(m0 + r) * lda + c0;
  const u16* ar1 = Ag + (size_t)(m0 + 64 + r) * lda + c0;
  const u16* brow = Bg + (size_t)(n0 + r) * ldb + c0;

  uint4 a0 = *(const uint4*)ar0, a1 = *(const uint4*)ar1, bv = *(const uint4*)brow;

  f32x4 acc[2][4];
#pragma unroll
  for (int i = 0; i < 2; i++)
#pragma unroll
    for (int j = 0; j < 4; j++) acc[i][j] = (f32x4){0.f, 0.f, 0.f, 0.f};

  for (int kt = 0; kt < K; kt += 32) {
    __syncthreads();
    *(uint4*)&As[r][c0] = a0;
    *(uint4*)&As[64 + r][c0] = a1;
    *(uint4*)&Bs[r][c0] = bv;
    int nk = kt + 32;
    if (nk < K) {
      a0 = *(const uint4*)(ar0 + nk);
      a1 = *(const uint4*)(ar1 + nk);
      bv = *(const uint4*)(brow + nk);
    }
    __syncthreads();
    short8 af[2], bf[4];
#pragma unroll
    for (int mt = 0; mt < 2; mt++) af[mt] = *(const short8*)&As[wm + mt * 16 + lr][lq * 8];
#pragma unroll
    for (int nt = 0; nt < 4; nt++) bf[nt] = *(const short8*)&Bs[nt * 16 + lr][lq * 8];
#pragma unroll
    for (int mt = 0; mt < 2; mt++)
#pragma unroll
      for (int nt = 0; nt < 4; nt++)
        acc[mt][nt] = __builtin_amdgcn_mfma_f32_16x16x32_bf16(af[mt], bf[nt], acc[mt][nt], 0, 0, 0);
  }

#pragma unroll
  for (int nt = 0; nt < 4; nt++) {
    int nn = n0 + nt * 16 + lr;
#pragma unroll
    for (int mt = 0; mt < 2; mt++) {
#pragma unroll
      for (int rr = 0; rr < 4; rr++) {
        int mm = m0 + wm + mt * 16 + lq * 4 + rr;
        C[(size_t)mm * ldc + nn] =
            __float2bfloat16(epi(acc[mt][nt][rr], mm, nn, bias, res, ldres, extra, extraDiv, alpha, mode));
      }
    }
  }
}

// ---------------------------------------------------------------------------
// Flash v7: v6 (r10) with split-private non-atomic output (no zero-init, no
// atomic RMW): o/l stored into per-split buffers, summed in fdiv.
// ---------------------------------------------------------------------------
__device__ __forceinline__ int swz(int row, int cg)
{
  return row * 64 + ((cg ^ (row & 3) ^ (((row >> 3) & 1) << 2)) << 3);
}

__global__ __launch_bounds__(256) void flash_k(
    const bf16* __restrict__ Qp, long long sQb, int sQr,
    const bf16* __restrict__ Kp, long long sKb, int sKr,
    const bf16* __restrict__ VTp, long long sVz,
    float* __restrict__ oAcc, long long sOb, long long sOsplit,
    float* __restrict__ lAcc, int Ml, int lSplit,
    const int* __restrict__ fog,
    int tilesPerSplit, int SkLen)
{
  __shared__ u16 Kl[64 * 64];
  __shared__ u16 Vl[64 * 64];
  __shared__ u16 fgl16[2304];

  const float SC = 0.125f * 1.44269504088896340736f;
  int z = blockIdx.y, b = z >> 3, h = z & 7;
  int qt = blockIdx.x;
  int split = blockIdx.z;
  int kt0 = split * tilesPerSplit;
  int t = threadIdx.x, lane = t & 63, w = t >> 6;
  int lr = lane & 15, lq = lane >> 4;
  int useMask = (fog != nullptr);

  const u16* Qg = (const u16*)Qp + (size_t)b * sQb + h * 64;
  const u16* Kg = (const u16*)Kp + (size_t)b * sKb + h * 64;
  const u16* Vg = (const u16*)VTp + (size_t)z * sVz;

  if (useMask) {
    for (int j = t; j < SkLen; j += 256) fgl16[j] = fog[b * 2304 + j] ? 0xFFFFu : 0u;
  }

  int qrow = qt * 64 + w * 16 + lr;
  short8 qf0, qf1;
  {
    union { short8 s; u16 u[8]; } i0, i1, o0, o1;
    i0.s = *(const short8*)(Qg + (size_t)qrow * sQr + lq * 8);
    i1.s = *(const short8*)(Qg + (size_t)qrow * sQr + 32 + lq * 8);
#pragma unroll
    for (int j = 0; j < 8; j++) {
      o0.u[j] = f2bits(b2f(i0.u[j]) * SC);
      o1.u[j] = f2bits(b2f(i1.u[j]) * SC);
    }
    qf0 = o0.s; qf1 = o1.s;
  }

  short8 ones8;
  {
    union { short8 s; u16 u[8]; } on;
#pragma unroll
    for (int j = 0; j < 8; j++) on.u[j] = 0x3F80u;
    ones8 = on.s;
  }

  int rowA[4], kAd0[4], kAd1[4];
#pragma unroll
  for (int nt = 0; nt < 4; nt++) {
    rowA[nt] = 32 * (nt >> 1) + 8 * (lr >> 2) + 4 * (nt & 1) + (lr & 3);
    kAd0[nt] = swz(rowA[nt], lq);
    kAd1[nt] = swz(rowA[nt], lq + 4);
  }
  int vAd0[4], vAd1[4];
#pragma unroll
  for (int dt = 0; dt < 4; dt++) {
    vAd0[dt] = swz(dt * 16 + lr, lq);
    vAd1[dt] = swz(dt * 16 + lr, lq + 4);
  }

  f32x4 o[4], ol;
#pragma unroll
  for (int i = 0; i < 4; i++) o[i] = (f32x4){0.f, 0.f, 0.f, 0.f};
  ol = (f32x4){0.f, 0.f, 0.f, 0.f};

  int rr = t >> 2, cg = t & 3, cs = cg * 8;
  int wAd0 = swz(rr, cg), wAd1 = swz(rr, cg + 4);

  const u16* krow = Kg + (size_t)(kt0 * 64 + rr) * sKr + cs;
  const u16* vrow = Vg + (size_t)rr * SkLen + kt0 * 64 + cs;
  uint4 ka = *(const uint4*)(krow);
  uint4 kb = *(const uint4*)(krow + 32);
  uint4 va = *(const uint4*)(vrow);
  uint4 vb = *(const uint4*)(vrow + 32);

  for (int kti = 0; kti < tilesPerSplit; kti++) {
    int kt = kt0 + kti;
    __syncthreads();
    *(uint4*)&Kl[wAd0] = ka;
    *(uint4*)&Kl[wAd1] = kb;
    *(uint4*)&Vl[wAd0] = va;
    *(uint4*)&Vl[wAd1] = vb;
    if (kti + 1 < tilesPerSplit) {
      krow += (size_t)64 * sKr;
      vrow += 64;
      ka = *(const uint4*)(krow);
      kb = *(const uint4*)(krow + 32);
      va = *(const uint4*)(vrow);
      vb = *(const uint4*)(vrow + 32);
    }
    __syncthreads();

    f32x4 s[4];
#pragma unroll
    for (int nt = 0; nt < 4; nt++) {
      s[nt] = (f32x4){0.f, 0.f, 0.f, 0.f};
      short8 kf0 = *(const short8*)&Kl[kAd0[nt]];
      short8 kf1 = *(const short8*)&Kl[kAd1[nt]];
      s[nt] = __builtin_amdgcn_mfma_f32_16x16x32_bf16(kf0, qf0, s[nt], 0, 0, 0);
      s[nt] = __builtin_amdgcn_mfma_f32_16x16x32_bf16(kf1, qf1, s[nt], 0, 0, 0);
    }

    union { unsigned int u[4]; short8 s8; } pk0, pk1;
#pragma unroll
    for (int nt = 0; nt < 4; nt++) {
      float p0 = __builtin_amdgcn_exp2f(s[nt][0]);
      float p1 = __builtin_amdgcn_exp2f(s[nt][1]);
      float p2 = __builtin_amdgcn_exp2f(s[nt][2]);
      float p3 = __builtin_amdgcn_exp2f(s[nt][3]);
      unsigned int w0 = pkbf(p0, p1);
      unsigned int w1 = pkbf(p2, p3);
      if (useMask) {
        int key = kt * 64 + 32 * (nt >> 1) + 8 * lq + 4 * (nt & 1);
        uint2 mm = *(const uint2*)&fgl16[key];
        w0 &= mm.x; w1 &= mm.y;
      }
      if (nt < 2) { pk0.u[(nt & 1) * 2] = w0; pk0.u[(nt & 1) * 2 + 1] = w1; }
      else        { pk1.u[(nt & 1) * 2] = w0; pk1.u[(nt & 1) * 2 + 1] = w1; }
    }
#pragma unroll
    for (int dt = 0; dt < 4; dt++) {
      short8 vf0 = *(const short8*)&Vl[vAd0[dt]];
      short8 vf1 = *(const short8*)&Vl[vAd1[dt]];
      o[dt] = __builtin_amdgcn_mfma_f32_16x16x32_bf16(pk0.s8, vf0, o[dt], 0, 0, 0);
      o[dt] = __builtin_amdgcn_mfma_f32_16x16x32_bf16(pk1.s8, vf1, o[dt], 0, 0, 0);
    }
    ol = __builtin_amdgcn_mfma_f32_16x16x32_bf16(pk0.s8, ones8, ol, 0, 0, 0);
    ol = __builtin_amdgcn_mfma_f32_16x16x32_bf16(pk1.s8, ones8, ol, 0, 0, 0);
  }

  float* lS = lAcc + (size_t)split * lSplit;
  if (lr == 0) {
#pragma unroll
    for (int r2 = 0; r2 < 4; r2++)
      lS[z * Ml + qt * 64 + w * 16 + lq * 4 + r2] = ol[r2];
  }

  float* ob = oAcc + (size_t)split * sOsplit + (size_t)b * sOb;
  int qb = qt * 64 + w * 16 + lq * 4;
#pragma unroll
  for (int dt = 0; dt < 4; dt++)
#pragma unroll
    for (int r2 = 0; r2 < 4; r2++)
      ob[(size_t)(qb + r2) * 512 + h * 64 + dt * 16 + lr] = o[dt][r2];
}

// normalize with split-sum, vectorized x4
__global__ __launch_bounds__(256) void fdiv4_k(const float* __restrict__ oAcc,
                                               const float* __restrict__ lAcc,
                                               int Mq, int Ml, int rows,
                                               bf16* __restrict__ out,
                                               int nsplit, long long oSplit, int lSplit)
{
  int i = (blockIdx.x * 256 + threadIdx.x) * 4;
  if (i >= rows * 512) return;
  int row = i >> 9, col = i & 511;
  int b = row / Mq, q = row - b * Mq;
  int zz = b * 8 + (col >> 6);
  float l = 0.f;
  float4 v = {0.f, 0.f, 0.f, 0.f};
  for (int s = 0; s < nsplit; s++) {
    l += lAcc[(size_t)s * lSplit + zz * Ml + q];
    float4 p = *(const float4*)(oAcc + (size_t)s * oSplit + i);
    v.x += p.x; v.y += p.y; v.z += p.z; v.w += p.w;
  }
  float inv = (l > 0.f) ? 1.f / l : 0.f;
  u16 o4[4] = {f2bits(v.x * inv), f2bits(v.y * inv), f2bits(v.z * inv), f2bits(v.w * inv)};
  unsigned int lo = o4[0] | ((unsigned)o4[1] << 16);
  unsigned int hi = o4[2] | ((unsigned)o4[3] << 16);
  *(uint2*)((u16*)out + i) = (uint2){lo, hi};
}

// fused bias assembly: out[5][1536] = {mem, layer0..3} x {q|k|v}
__global__ void biasfuse_k(const bf16* __restrict__ mbq, const bf16* __restrict__ mbk,
                           const bf16* __restrict__ mbv, const bf16* __restrict__ lbq,
                           const bf16* __restrict__ lbk, const bf16* __restrict__ lbv,
                           bf16* __restrict__ out)
{
  int j = blockIdx.x * 256 + threadIdx.x;
  if (j >= 5 * 1536) return;
  int g = j / 1536, r = j - g * 1536;
  int which = r >> 9, c = r & 511;
  const bf16* src;
  if (g == 0) src = (which == 0) ? mbq : (which == 1) ? mbk : mbv;
  else {
    const bf16* base = (which == 0) ? lbq : (which == 1) ? lbk : lbv;
    src = base + (g - 1) * 512;
  }
  out[j] = src[c];
}

// in [R,C] row-major -> out [C,Rpad], zero-filled for src rows >= R
__global__ __launch_bounds__(256) void transpose_k(const bf16* __restrict__ in, bf16* __restrict__ out,
                                                   int R, int C, int Rpad, long long inB, long long outB)
{
  __shared__ u16 tile[32][33];
  const u16* ip = (const u16*)in + (size_t)blockIdx.z * inB;
  u16* op = (u16*)out + (size_t)blockIdx.z * outB;
  int c0 = blockIdx.x * 32, r0 = blockIdx.y * 32;
  int tx = threadIdx.x & 31, ty = threadIdx.x >> 5;
#pragma unroll
  for (int j = 0; j < 4; j++) {
    int rr = r0 + ty + j * 8, cc = c0 + tx;
    u16 v = 0;
    if (rr < R && cc < C) v = ip[(size_t)rr * C + cc];
    tile[ty + j * 8][tx] = v;
  }
  __syncthreads();
#pragma unroll
  for (int j = 0; j < 4; j++) {
    int oc = c0 + ty + j * 8;
    if (oc < C && r0 + tx < Rpad) op[(size_t)oc * Rpad + r0 + tx] = tile[tx][ty + j * 8];
  }
}

// head-slice transpose with input row stride
__global__ __launch_bounds__(256) void headT_k(const bf16* __restrict__ in, bf16* __restrict__ out,
                                               int Sk, int rowbase, int bstride, int instride)
{
  __shared__ u16 tile[32][33];
  int z = blockIdx.z, b = z >> 3, h = z & 7;
  const u16* ip = (const u16*)in + ((size_t)(rowbase + b * bstride)) * instride + h * 64;
  u16* op = (u16*)out + (size_t)z * 64 * Sk;
  int r0 = blockIdx.x * 32, c0 = blockIdx.y * 32;
  int tx = threadIdx.x & 31, ty = threadIdx.x >> 5;
#pragma unroll
  for (int j = 0; j < 4; j++)
    tile[ty + j * 8][tx] = ip[(size_t)(r0 + ty + j * 8) * instride + c0 + tx];
  __syncthreads();
#pragma unroll
  for (int j = 0; j < 4; j++)
    op[(size_t)(c0 + ty + j * 8) * Sk + r0 + tx] = tile[tx][ty + j * 8];
}

// row LayerNorm over D=512, 4 rows/block (wave per row)
__global__ __launch_bounds__(256) void ln_k(const bf16* __restrict__ in, const bf16* __restrict__ g,
                                            const bf16* __restrict__ bb, bf16* __restrict__ out)
{
  size_t row = blockIdx.x * 4 + (threadIdx.x >> 6);
  int lane = threadIdx.x & 63;
  const u16* ip = (const u16*)in + row * 512 + lane * 8;
  uint4 rv = *(const uint4*)ip;
  float v[8];
  unpk(rv.x, v[0], v[1]); unpk(rv.y, v[2], v[3]); unpk(rv.z, v[4], v[5]); unpk(rv.w, v[6], v[7]);
  float s = 0.f, s2 = 0.f;
#pragma unroll
  for (int k = 0; k < 8; k++) { s += v[k]; s2 += v[k] * v[k]; }
#pragma unroll
  for (int o = 32; o; o >>= 1) { s += __shfl_xor(s, o); s2 += __shfl_xor(s2, o); }
  float mean = s * (1.f / 512.f);
  float var = s2 * (1.f / 512.f) - mean * mean;
  float rstd = rsqrtf(var + 1e-5f);
  uint4 gv = *(const uint4*)((const u16*)g + lane * 8);
  uint4 bv = *(const uint4*)((const u16*)bb + lane * 8);
  float gf[8], bf2[8];
  unpk(gv.x, gf[0], gf[1]); unpk(gv.y, gf[2], gf[3]); unpk(gv.z, gf[4], gf[5]); unpk(gv.w, gf[6], gf[7]);
  unpk(bv.x, bf2[0], bf2[1]); unpk(bv.y, bf2[2], bf2[3]); unpk(bv.z, bf2[4], bf2[5]); unpk(bv.w, bf2[6], bf2[7]);
  u16 o8[8];
#pragma unroll
  for (int k = 0; k < 8; k++) o8[k] = f2bits((v[k] - mean) * rstd * gf[k] + bf2[k]);
  uint4 ov;
  ov.x = o8[0] | ((unsigned)o8[1] << 16); ov.y = o8[2] | ((unsigned)o8[3] << 16);
  ov.z = o8[4] | ((unsigned)o8[5] << 16); ov.w = o8[6] | ((unsigned)o8[7] << 16);
  *(uint4*)((u16*)out + row * 512 + lane * 8) = ov;
}

__global__ void glob_k(const bf16* __restrict__ gf, const bf16* __restrict__ gw,
                       const bf16* __restrict__ gb, float* __restrict__ out)
{
  int i = blockIdx.x * 256 + threadIdx.x; if (i >= 1024) return;
  int b = i >> 9, d = i & 511;
  float s = (float)gb[d];
#pragma unroll
  for (int f = 0; f < 7; f++) s += (float)gf[b * 7 + f] * (float)gw[f * 512 + d];
  out[i] = s;
}

__global__ void padA_k(const bf16* __restrict__ in, bf16* __restrict__ out)
{
  int i = blockIdx.x * 256 + threadIdx.x; if (i >= 4608 * 160) return;
  int r = i / 160, c = i - r * 160;
  out[i] = (c < 150) ? in[r * 150 + c] : __float2bfloat16(0.f);
}

__global__ void catg_k(const bf16* __restrict__ mem, const bf16* __restrict__ mu, bf16* __restrict__ out)
{
  int i = blockIdx.x * 256 + threadIdx.x; if (i >= 256 * 1024) return;
  int r = i >> 10, c = i & 1023;
  out[i] = (c < 512) ? mem[r * 512 + c] : mu[r * 512 + c - 512];
}

__global__ void gcomb_k(const bf16* __restrict__ g, const bf16* __restrict__ mu,
                        const bf16* __restrict__ mem, bf16* __restrict__ out)
{
  int i = blockIdx.x * 256 + threadIdx.x; if (i >= 131072) return;
  float gg = (float)g[i];
  out[i] = __float2bfloat16(gg * (float)mu[i] + (1.f - gg) * (float)mem[i]);
}

__global__ __launch_bounds__(64) void plog_k(const bf16* __restrict__ x, const bf16* __restrict__ pw,
                                             const bf16* __restrict__ pb, float* __restrict__ out)
{
  size_t row = blockIdx.x; int lane = threadIdx.x;
  uint4 xv = *(const uint4*)((const u16*)x + row * 512 + lane * 8);
  uint4 wv = *(const uint4*)((const u16*)pw + lane * 8);
  float v[8], w[8];
  unpk(xv.x, v[0], v[1]); unpk(xv.y, v[2], v[3]); unpk(xv.z, v[4], v[5]); unpk(xv.w, v[6], v[7]);
  unpk(wv.x, w[0], w[1]); unpk(wv.y, w[2], w[3]); unpk(wv.z, w[4], w[5]); unpk(wv.w, w[6], w[7]);
  float s = 0.f;
#pragma unroll
  for (int k = 0; k < 8; k++) s += v[k] * w[k];
#pragma unroll
  for (int o = 32; o; o >>= 1) s += __shfl_xor(s, o);
  if (lane == 0) out[row] = s + (float)pb[0];
}

__global__ __launch_bounds__(256) void psm_k(const float* __restrict__ lg, float* __restrict__ pw)
{
  __shared__ float red[4];
  int b = blockIdx.x, tid = threadIdx.x;
  const float* p = lg + b * 2304;
  float vals[9]; float mx = -3e38f;
#pragma unroll
  for (int i = 0; i < 9; i++) {
    int j = tid + i * 256;
    float x = (j < 2304) ? p[j] : -3e38f;
    vals[i] = x; mx = fmaxf(mx, x);
  }
#pragma unroll
  for (int o = 32; o; o >>= 1) mx = fmaxf(mx, __shfl_xor(mx, o));
  if ((tid & 63) == 0) red[tid >> 6] = mx;
  __syncthreads();
  mx = fmaxf(fmaxf(red[0], red[1]), fmaxf(red[2], red[3]));
  float sum = 0.f;
#pragma unroll
  for (int i = 0; i < 9; i++) {
    int j = tid + i * 256;
    if (j < 2304) { float e = expf(vals[i] - mx); vals[i] = e; sum += e; }
  }
  __syncthreads();
#pragma unroll
  for (int o = 32; o; o >>= 1) sum += __shfl_xor(sum, o);
  if ((tid & 63) == 0) red[tid >> 6] = sum;
  __syncthreads();
  sum = red[0] + red[1] + red[2] + red[3];
  float inv = 1.f / sum;
#pragma unroll
  for (int i = 0; i < 9; i++) {
    int j = tid + i * 256;
    if (j < 2304) pw[b * 2304 + j] = vals[i] * inv;
  }
}

__global__ __launch_bounds__(256) void pool1_k(const float* __restrict__ pw, const bf16* __restrict__ x,
                                               float* __restrict__ out)
{
  int b = blockIdx.y, chunk = blockIdx.x, t = threadIdx.x;
  float a0 = 0.f, a1 = 0.f;
  for (int s = 0; s < 64; s++) {
    int tok = chunk * 64 + s;
    float wv = pw[b * 2304 + tok];
    const u16* xp = (const u16*)x + ((size_t)(b * 2304 + tok)) * 512;
    a0 += wv * b2f(xp[t]);
    a1 += wv * b2f(xp[t + 256]);
  }
  atomicAdd(&out[b * 512 + t], a0);
  atomicAdd(&out[b * 512 + t + 256], a1);
}

__global__ void heads_k(const float* __restrict__ pooled,
                        const bf16* w0, const bf16* b0, const bf16* w1, const bf16* b1,
                        const bf16* w2, const bf16* b2, const bf16* w3, const bf16* b3,
                        const bf16* w4, const bf16* b4, const bf16* w5, const bf16* b5,
                        const bf16* w6, const bf16* b6, const bf16* w7, const bf16* b7,
                        void* __restrict__ outv, const int* __restrict__ flag)
{
  int idx = blockIdx.x * 256 + threadIdx.x; if (idx >= 444) return;
  const bf16* W[8] = {w0, w1, w2, w3, w4, w5, w6, w7};
  const bf16* Bi[8] = {b0, b1, b2, b3, b4, b5, b6, b7};
  int b = idx / 222, j = idx - b * 222;
  const int sizes[8]  = {48, 48, 48, 48, 8, 20, 1, 1};
  const int outoff[8] = {0, 96, 192, 288, 384, 400, 440, 442};
  int h = 0, basec = 0;
  while (h < 7 && j >= basec + sizes[h]) { basec += sizes[h]; ++h; }
  int col = j - basec;
  const bf16* wp = W[h]; int nc = sizes[h];
  float s = (float)Bi[h][col];
  for (int k = 0; k < 512; k++) s += pooled[b * 512 + k] * (float)wp[k * nc + col];
  int e = outoff[h] + b * nc + col;
  if (flag[0]) ((bf16*)outv)[e] = __float2bfloat16(s);
  else         ((float*)outv)[e] = s;
}

__global__ void outstore_k(const bf16* __restrict__ nm, void* __restrict__ outv,
                           const int* __restrict__ flag)
{
  int i = blockIdx.x * 256 + threadIdx.x; if (i >= 131072) return;
  if (flag[0]) ((bf16*)outv)[444 + i] = nm[i];
  else         ((float*)outv)[444 + i] = (float)nm[i];
}

// ---------------------------------------------------------------------------

static inline void gemm(hipStream_t st, const bf16* A, int lda, long long sAb, long long sAh,
                        const bf16* B, int ldb, long long sBb, long long sBh,
                        bf16* C, int ldc, long long sCb, long long sCh,
                        int M, int N, int K, int BZ, int HZ,
                        const bf16* bias, const bf16* res, int ldres,
                        const float* extra, int extraDiv, float alpha, int mode)
{
  dim3 g((N + 63) / 64, (M + 63) / 64, BZ * HZ);
  gemm_k<<<g, dim3(256), 0, st>>>(A, lda, sAb, sAh, B, ldb, sBb, sBh, C, ldc, sCb, sCh,
                                  M, N, K, HZ, bias, res, ldres, extra, extraDiv, alpha, mode);
}

static inline void gemmM128(hipStream_t st, const bf16* A, int lda, const bf16* B, int ldb,
                            bf16* C, int ldc, int M, int N, int K,
                            const bf16* bias, const bf16* res, int ldres,
                            const float* extra, int extraDiv, float alpha, int mode)
{
  dim3 g(N / 64, M / 128, 1);
  gemmM128_k<<<g, dim3(256), 0, st>>>(A, lda, B, ldb, C, ldc, K, bias, res, ldres,
                                      extra, extraDiv, alpha, mode);
}

static inline void transp(hipStream_t st, const bf16* in, bf16* out, int R, int C, int Rpad,
                          long long inB, long long outB, int Z)
{
  dim3 g((C + 31) / 32, (Rpad + 31) / 32, Z);
  transpose_k<<<g, dim3(256), 0, st>>>(in, out, R, C, Rpad, inB, outB);
}

extern "C" void kernel_launch(void* const* d_in, const int* in_sizes, int n_in,
                              void* d_out, int out_size, void* d_ws, size_t ws_size,
                              hipStream_t stream)
{
  (void)in_sizes; (void)n_in; (void)out_size;
  const int* fog = (const int*)d_in[3];

  static const int kSz[55] = {
    691200, 14, 131072, 76800, 512, 3584, 512,
    262144, 512, 262144, 512, 262144, 512, 262144, 512,
    524288, 512, 512, 512, 512, 512,
    1048576, 2048, 1048576, 2048, 1048576, 2048, 1048576, 2048,
    2048, 2048, 2048, 2048,
    4194304, 8192, 4194304, 2048,
    512, 1,
    24576, 48, 24576, 48, 24576, 48, 24576, 48,
    4096, 8, 10240, 20, 512, 1, 512, 1};
  static const int kIdx[55] = {
    0, 1, 2, 4, 5, 6, 7,
    8, 9, 10, 11, 12, 13, 14, 15,
    16, 17, 18, 19, 20, 21,
    22, 23, 24, 25, 26, 27, 28, 29,
    30, 31, 32, 33,
    34, 35, 36, 37,
    38, 39,
    40, 41, 42, 43, 44, 45, 46, 47,
    48, 49, 50, 51, 52, 53, 54, 55};

  CvtArgs ca;
  size_t cum[55]; int coffi = 0;
  for (int t = 0; t < 55; t++) {
    cum[t] = (size_t)coffi;
    ca.p[t] = d_in[kIdx[t]];
    ca.off[t] = coffi;
    ca.sz[t] = kSz[t];
    coffi += (kSz[t] + 7) & ~7;
  }
  ca.off[55] = coffi;
  size_t coff = (size_t)coffi;

  const int S = 2304, NROW = 4608, CATROW = 4864;
  const long long QR = 1536;
  const long long RSQ = (long long)S * QR;
  const long long OSPLIT = (long long)NROW * 512;

  char* basep = (char*)d_ws; size_t off = 0;
  auto alloc = [&](size_t elems, size_t esz) -> void* {
    void* p = basep + off; off += (elems * esz + 255) & ~(size_t)255; return p;
  };

  bf16* canon = (bf16*)alloc(coff, 2);
  int* dflag = (int*)alloc(64, 4);
  bf16* tHex = (bf16*)alloc(512 * 160, 2);
  bf16* aPad = (bf16*)alloc((size_t)NROW * 160, 2);
  bf16* tQKVmem = (bf16*)alloc(1536 * 512, 2);
  bf16* tWo = (bf16*)alloc(512 * 512, 2);
  bf16* tGate = (bf16*)alloc(512 * 1024, 2);
  bf16* tLqkv = (bf16*)alloc(4ULL * 1536 * 512, 2);
  bf16* tLo = (bf16*)alloc(4 * 512 * 512, 2);
  bf16* tF1 = (bf16*)alloc(4ULL * 2048 * 512, 2);
  bf16* tF2 = (bf16*)alloc(4ULL * 512 * 2048, 2);
  bf16* fbias = (bf16*)alloc(5 * 1536, 2);
  float* globF = (float*)alloc(1024, 4);
  bf16* catX = (bf16*)alloc((size_t)CATROW * 512, 2);
  bf16* QKV = (bf16*)alloc((size_t)CATROW * 1536, 2);
  bf16* VmemT = (bf16*)alloc(16ULL * 64 * 128, 2);
  bf16* VsT = (bf16*)alloc(16ULL * 64 * S, 2);
  bf16* mo = (bf16*)alloc((size_t)NROW * 512, 2);
  bf16* tmp1 = (bf16*)alloc((size_t)NROW * 512, 2);
  bf16* xbuf = (bf16*)alloc((size_t)NROW * 512, 2);
  bf16* x2buf = (bf16*)alloc((size_t)NROW * 512, 2);
  bf16* mu0 = (bf16*)alloc(256 * 512, 2);
  bf16* mup = (bf16*)alloc(256 * 512, 2);
  bf16* catg = (bf16*)alloc(256 * 1024, 2);
  bf16* gateb = (bf16*)alloc(256 * 512, 2);
  bf16* nmpre = (bf16*)alloc(256 * 512, 2);
  bf16* nmout = (bf16*)alloc(256 * 512, 2);
  float* plog = (float*)alloc(NROW, 4);
  float* pwv = (float*)alloc(NROW, 4);
  float* pooledF = (float*)alloc(1024, 4);
  float* oAcc = (float*)alloc(3ULL * NROW * 512, 4);
  float* lAcc = (float*)alloc(131072, 4);
  bf16* hbuf = (bf16*)alloc((size_t)NROW * 2048, 2);
  if (off > ws_size) return;

  detect_k<<<1, 512, 0, stream>>>((const unsigned int*)d_in[0], dflag);
  cvtall8_k<<<(coffi / 8 + 255) / 256, 256, 0, stream>>>(ca, canon, dflag);

  auto T = [&](int t) -> const bf16* { return canon + cum[t]; };
  const bf16* map_rep = T(0);
  const bf16* gfeat   = T(1);
  const bf16* memin   = T(2);
  const bf16* hex_w = T(3);  const bf16* hex_b = T(4);
  const bf16* glob_w = T(5); const bf16* glob_b = T(6);
  const bf16* mem_wq = T(7);  const bf16* mem_bq = T(8);
  const bf16* mem_wk = T(9);  const bf16* mem_bk = T(10);
  const bf16* mem_wv = T(11); const bf16* mem_bv = T(12);
  const bf16* mem_wo = T(13); const bf16* mem_bo = T(14);
  const bf16* gate_w = T(15); const bf16* gate_b = T(16);
  const bf16* mn1_g = T(17); const bf16* mn1_b = T(18);
  const bf16* mn2_g = T(19); const bf16* mn2_b = T(20);
  const bf16* lw_q = T(21); const bf16* lb_q = T(22);
  const bf16* lw_k = T(23); const bf16* lb_k = T(24);
  const bf16* lw_v = T(25); const bf16* lb_v = T(26);
  const bf16* lw_o = T(27); const bf16* lb_o = T(28);
  const bf16* ln1_g = T(29); const bf16* ln1_b = T(30);
  const bf16* ln2_g = T(31); const bf16* ln2_b = T(32);
  const bf16* ff1_w = T(33); const bf16* ff1_b = T(34);
  const bf16* ff2_w = T(35); const bf16* ff2_b = T(36);
  const bf16* pool_w = T(37); const bf16* pool_b = T(38);

  // ---- weight transposes (fused QKV blocks) + fused biases ----
  transp(stream, hex_w, tHex, 150, 512, 160, 0, 0, 1);
  transp(stream, mem_wq, tQKVmem, 512, 512, 512, 0, 0, 1);
  transp(stream, mem_wk, tQKVmem + 262144, 512, 512, 512, 0, 0, 1);
  transp(stream, mem_wv, tQKVmem + 524288, 512, 512, 512, 0, 0, 1);
  transp(stream, mem_wo, tWo, 512, 512, 512, 0, 0, 1);
  transp(stream, gate_w, tGate, 1024, 512, 1024, 0, 0, 1);
  transp(stream, lw_q, tLqkv, 512, 512, 512, 262144, 786432, 4);
  transp(stream, lw_k, tLqkv + 262144, 512, 512, 512, 262144, 786432, 4);
  transp(stream, lw_v, tLqkv + 524288, 512, 512, 512, 262144, 786432, 4);
  transp(stream, lw_o, tLo, 512, 512, 512, 262144, 262144, 4);
  transp(stream, ff1_w, tF1, 512, 2048, 512, 1048576, 1048576, 4);
  transp(stream, ff2_w, tF2, 2048, 512, 2048, 1048576, 1048576, 4);
  biasfuse_k<<<(5 * 1536 + 255) / 256, 256, 0, stream>>>(mem_bq, mem_bk, mem_bv,
                                                         lb_q, lb_k, lb_v, fbias);

  // ---- seq = map@hex_w + hex_b + glob ----
  glob_k<<<4, 256, 0, stream>>>(gfeat, glob_w, glob_b, globF);
  padA_k<<<(NROW * 160 + 255) / 256, 256, 0, stream>>>(map_rep, aPad);
  gemm(stream, aPad, 160, 0, 0, tHex, 160, 0, 0, catX, 512, 0, 0,
       NROW, 512, 160, 1, 1, hex_b, nullptr, 0, globF, S, 1.f, 1);
  hipMemcpyAsync(catX + (size_t)NROW * 512, memin, 256 * 512 * 2, hipMemcpyDeviceToDevice, stream);

  // ---- fused shared-weight QKV over [seq ; memory] (M=4864=38*128) ----
  gemmM128(stream, catX, 512, tQKVmem, 512, QKV, 1536, CATROW, 1536, 512,
           fbias, nullptr, 0, nullptr, 1, 1.f, 0);

  // ---- mem_out = MHA(seq, memory, memory), flash ----
  headT_k<<<dim3(4, 2, 16), 256, 0, stream>>>(QKV + 1024, VmemT, 128, NROW, 128, 1536);
  flash_k<<<dim3(36, 16, 1), 256, 0, stream>>>(
      QKV, RSQ, 1536, QKV + (size_t)NROW * 1536 + 512, 128 * QR, 1536,
      VmemT, 64 * 128, oAcc, (long long)S * 512, OSPLIT, lAcc, 2304, 16 * 2304,
      nullptr, 2, 128);
  fdiv4_k<<<(NROW * 128 + 255) / 256, 256, 0, stream>>>(oAcc, lAcc, 2304, 2304, NROW, mo,
                                                        1, OSPLIT, 16 * 2304);
  gemm(stream, mo, 512, 0, 0, tWo, 512, 0, 0, tmp1, 512, 0, 0,
       NROW, 512, 512, 1, 1, mem_bo, catX, 512, nullptr, 1, 1.f, 4);
  ln_k<<<NROW / 4, 256, 0, stream>>>(tmp1, mn1_g, mn1_b, xbuf);

  // ---- mem_upd = MHA(memory, seq, seq), flash split-6 + gated update ----
  headT_k<<<dim3(72, 2, 16), 256, 0, stream>>>(QKV + 1024, VsT, S, 0, S, 1536);
  flash_k<<<dim3(2, 16, 6), 256, 0, stream>>>(
      QKV + (size_t)NROW * 1536, 128 * QR, 1536, QKV + 512, RSQ, 1536,
      VsT, 64LL * S, oAcc, 128 * 512, 128 * 512 * 16LL, lAcc, 128, 16 * 128,
      nullptr, 6, S);
  fdiv4_k<<<(256 * 128 + 255) / 256, 256, 0, stream>>>(oAcc, lAcc, 128, 128, 256, mu0,
                                                       6, 128 * 512 * 16LL, 16 * 128);
  gemm(stream, mu0, 512, 0, 0, tWo, 512, 0, 0, mup, 512, 0, 0,
       256, 512, 512, 1, 1, mem_bo, nullptr, 0, nullptr, 1, 1.f, 0);
  catg_k<<<(256 * 1024 + 255) / 256, 256, 0, stream>>>(memin, mup, catg);
  gemm(stream, catg, 1024, 0, 0, tGate, 1024, 0, 0, gateb, 512, 0, 0,
       256, 512, 1024, 1, 1, gate_b, nullptr, 0, nullptr, 1, 1.f, 5);
  gcomb_k<<<(131072 + 255) / 256, 256, 0, stream>>>(gateb, mup, memin, nmpre);
  ln_k<<<64, 256, 0, stream>>>(nmpre, mn2_g, mn2_b, nmout);
  outstore_k<<<(131072 + 255) / 256, 256, 0, stream>>>(nmout, d_out, dflag);

  // ---- transformer layers ----
  for (int l = 0; l < 4; l++) {
    gemmM128(stream, xbuf, 512, tLqkv + (size_t)l * 786432, 512, QKV, 1536,
             NROW, 1536, 512, fbias + (1 + l) * 1536, nullptr, 0, nullptr, 1, 1.f, 0);
    headT_k<<<dim3(72, 2, 16), 256, 0, stream>>>(QKV + 1024, VsT, S, 0, S, 1536);
    flash_k<<<dim3(36, 16, 3), 256, 0, stream>>>(
        QKV, RSQ, 1536, QKV + 512, RSQ, 1536,
        VsT, 64LL * S, oAcc, (long long)S * 512, OSPLIT, lAcc, 2304, 16 * 2304,
        fog, 12, S);
    fdiv4_k<<<(NROW * 128 + 255) / 256, 256, 0, stream>>>(oAcc, lAcc, 2304, 2304, NROW, mo,
                                                          3, OSPLIT, 16 * 2304);
    gemm(stream, mo, 512, 0, 0, tLo + (size_t)l * 262144, 512, 0, 0, tmp1, 512, 0, 0,
         NROW, 512, 512, 1, 1, lb_o + l * 512, xbuf, 512, nullptr, 1, 1.f, 4);
    ln_k<<<NROW / 4, 256, 0, stream>>>(tmp1, ln1_g + l * 512, ln1_b + l * 512, x2buf);
    gemmM128(stream, x2buf, 512, tF1 + (size_t)l * 1048576, 512, hbuf, 2048,
             NROW, 2048, 512, ff1_b + l * 2048, nullptr, 0, nullptr, 1, 1.f, 2);
    gemm(stream, hbuf, 2048, 0, 0, tF2 + (size_t)l * 1048576, 2048, 0, 0, tmp1, 512, 0, 0,
         NROW, 512, 2048, 1, 1, ff2_b + l * 512, x2buf, 512, nullptr, 1, 1.f, 4);
    ln_k<<<NROW / 4, 256, 0, stream>>>(tmp1, ln2_g + l * 512, ln2_b + l * 512, xbuf);
  }

  // ---- attention pooling + heads ----
  plog_k<<<NROW, 64, 0, stream>>>(xbuf, pool_w, pool_b, plog);
  psm_k<<<2, 256, 0, stream>>>(plog, pwv);
  hipMemsetAsync(pooledF, 0, 1024 * sizeof(float), stream);
  pool1_k<<<dim3(36, 2), 256, 0, stream>>>(pwv, xbuf, pooledF);

  heads_k<<<2, 256, 0, stream>>>(pooledF,
      T(39), T(40), T(41), T(42), T(43), T(44), T(45), T(46),
      T(47), T(48), T(49), T(50), T(51), T(52), T(53), T(54),
      d_out, dflag);
}